// Round 4
// baseline (3255.574 us; speedup 1.0000x reference)
//
#include <hip/hip_runtime.h>
#include <math.h>

// Problem dims (fixed)
#define B_ 2
#define C_ 2048
#define M_ 1024
#define H_ 16
#define KV_ 64
#define F_ 4096

typedef __attribute__((ext_vector_type(8))) __bf16 bf16x8;
typedef __attribute__((ext_vector_type(4))) float f32x4;
typedef unsigned short u16;

#if defined(__has_builtin)
#if __has_builtin(__builtin_amdgcn_mfma_f64_16x16x4f64)
#define HAVE_MFMA64 1
#endif
#endif
#ifndef HAVE_MFMA64
#define HAVE_MFMA64 0
#endif

#if HAVE_MFMA64
typedef __attribute__((ext_vector_type(4))) double f64x4;
#endif

__device__ __forceinline__ float bf2f(u16 u) {
    union { unsigned int i; float f; } x; x.i = ((unsigned int)u) << 16; return x.f;
}
__device__ __forceinline__ u16 f2bf(float f) {
    union { float f; unsigned int i; } x; x.f = f;
    unsigned int r = x.i + 0x7fffu + ((x.i >> 16) & 1u);
    return (u16)(r >> 16);
}
__device__ __forceinline__ float ldflag(const void* p, size_t i, int isf) {
    return isf ? ((const float*)p)[i] : bf2f(((const u16*)p)[i]);
}

__device__ __forceinline__ double blockReduceSumD(double v, double* red, int tid) {
#pragma unroll
    for (int off = 32; off > 0; off >>= 1) v += __shfl_down(v, off, 64);
    if ((tid & 63) == 0) red[tid >> 6] = v;
    __syncthreads();
    v = red[0] + red[1] + red[2] + red[3];
    __syncthreads();
    return v;
}

// ---------------------------------------------------------------------------
// Input-dtype detector (fires fp32 on this harness). flags[0]=1 iff fp32.
// ---------------------------------------------------------------------------
__global__ void detect_dtype(const unsigned int* __restrict__ w, int* __restrict__ flags) {
    __shared__ int cnt[256];
    int t = threadIdx.x, c = 0;
    for (int i = t; i < 2048; i += 256) {
        unsigned int e = (w[i] >> 7) & 0xffu;
        if (e >= 140u || (e > 0u && e < 91u)) c++;
    }
    cnt[t] = c; __syncthreads();
    for (int s = 128; s > 0; s >>= 1) { if (t < s) cnt[t] += cnt[t + s]; __syncthreads(); }
    if (t == 0) flags[0] = (cnt[0] > 300) ? 1 : 0;
}

// ---------------------------------------------------------------------------
// f64 MFMA self-calibration.
// cal[0] = 1 iff the fragment mapping was decoded AND end-to-end verified.
// cal[1] = 1 iff additionally the mapping is the STANDARD CDNA map:
//   A row=l&15,k=l>>4; B n=l&15,k=l>>4; D col=l&15,row=4*(l>>4)+reg
//   (identical to the verified bf16 16x16x32 C/D map -> softmax state
//    transfers to bf16-MFMA PV accumulators with no rearrangement).
// cal[16 + lane*12 + {0..8}] = {am, ak, bn, bk, colD, rowD0..rowD3}.
// ---------------------------------------------------------------------------
__device__ __forceinline__ float sAval(int m, int k) { return (float)(((m * 5 + k * 3) % 7) - 3); }
__device__ __forceinline__ float sBval(int k, int n) { return (float)(((k * 11 + n * 2) % 5) - 2); }
__device__ __forceinline__ float sQval(int m, int k) { return (float)(((m * 3 + k * 7) % 9) - 4); }
__device__ __forceinline__ float sKval(int c, int k) { return (float)(((c * 5 + k * 2) % 8) - 3); }

__global__ __launch_bounds__(256) void calibrate(int* __restrict__ cal) {
#if HAVE_MFMA64
    __shared__ int ctab[64][12];
    __shared__ int s_ok, s_bad, s_std;
    __shared__ float Ast[32][65], Bs[32][65];
    __shared__ float Qv[64][65], Kv[64][65];
    const int t = threadIdx.x;
    if (t == 0) { s_ok = 0; s_bad = 0; s_std = 0; }
    __syncthreads();
    if (t < 64) {
        const int l = t;
        f64x4 z = {0.0, 0.0, 0.0, 0.0};
        f64x4 p1 = __builtin_amdgcn_mfma_f64_16x16x4f64(1.0, (double)l, z, 0, 0, 0);
        f64x4 p2 = __builtin_amdgcn_mfma_f64_16x16x4f64((double)l, 1.0, z, 0, 0, 0);
        int ok = 1, bFam = 0, aFam = 0;
        int colD[4], rowD[4];
#pragma unroll
        for (int r = 0; r < 4; r++) {
            double pv = p1[r];
            int f = 0, n = 0;
            if (pv >= 0.0 && pv <= 4096.0) {
                long long vi = (long long)(pv + 0.5);
                if (vi >= 96 && vi <= 156 && ((vi - 96) & 3) == 0) { f = 1; n = (int)((vi - 96) >> 2); }
                else if (vi >= 6 && vi <= 246 && ((vi - 6) & 15) == 0) { f = 2; n = (int)((vi - 6) >> 4); }
            }
            if (f == 0) ok = 0;
            if (r == 0) bFam = f; else if (f != bFam) ok = 0;
            colD[r] = n;
            pv = p2[r]; f = 0; n = 0;
            if (pv >= 0.0 && pv <= 4096.0) {
                long long wi = (long long)(pv + 0.5);
                if (wi >= 96 && wi <= 156 && ((wi - 96) & 3) == 0) { f = 1; n = (int)((wi - 96) >> 2); }
                else if (wi >= 6 && wi <= 246 && ((wi - 6) & 15) == 0) { f = 2; n = (int)((wi - 6) >> 4); }
            }
            if (f == 0) ok = 0;
            if (r == 0) aFam = f; else if (f != aFam) ok = 0;
            rowD[r] = n;
        }
        if (colD[1] != colD[0] || colD[2] != colD[0] || colD[3] != colD[0]) ok = 0;
        int rm = (1 << rowD[0]) | (1 << rowD[1]) | (1 << rowD[2]) | (1 << rowD[3]);
        if (__popc(rm) != 4) ok = 0;
        int cm = 1 << colD[0];
#pragma unroll
        for (int off = 1; off < 16; off <<= 1) {
#pragma unroll
            for (int r = 0; r < 4; r++)
                if (__shfl_xor(rowD[r], off, 64) != rowD[r]) ok = 0;
            cm |= __shfl_xor(cm, off, 64);
        }
        if (cm != 0xffff) ok = 0;
        const int am = (aFam == 2) ? (l >> 2) : (l & 15);
        const int ak = (aFam == 2) ? (l & 3) : (l >> 4);
        const int bn = (bFam == 2) ? (l >> 2) : (l & 15);
        const int bk = (bFam == 2) ? (l & 3) : (l >> 4);
        // probe 3: exact end-to-end check of the decoded mapping
        {
            double a3 = (double)sAval(am, ak);
            double b3 = (double)sBval(bk, bn);
            f64x4 p3 = __builtin_amdgcn_mfma_f64_16x16x4f64(a3, b3, z, 0, 0, 0);
#pragma unroll
            for (int r = 0; r < 4; r++) {
                double ref = 0.0;
                for (int k2 = 0; k2 < 4; k2++)
                    ref += (double)sAval(rowD[r], k2) * (double)sBval(k2, colD[0]);
                if (p3[r] != ref) ok = 0;
            }
        }
        int isStd = ok;
        isStd &= (am == (l & 15)) && (ak == (l >> 4));
        isStd &= (bn == (l & 15)) && (bk == (l >> 4));
        isStd &= (colD[0] == (l & 15));
#pragma unroll
        for (int r = 0; r < 4; r++) isStd &= (rowD[r] == 4 * (l >> 4) + r);
        unsigned long long bb = __ballot(ok != 0);
        unsigned long long bstd = __ballot(isStd != 0);
        ctab[l][0] = am; ctab[l][1] = ak; ctab[l][2] = bn; ctab[l][3] = bk;
        ctab[l][4] = colD[0];
        ctab[l][5] = rowD[0]; ctab[l][6] = rowD[1]; ctab[l][7] = rowD[2]; ctab[l][8] = rowD[3];
        ctab[l][9] = 0; ctab[l][10] = 0; ctab[l][11] = 0;
        if (l == 0) { s_ok = (bb == ~0ull) ? 1 : 0; s_std = (bstd == ~0ull) ? 1 : 0; }
    }
    __syncthreads();
    // synthetic tiles for the structural verification
    for (int i = t; i < 32 * 64; i += 256) {
        int k2 = i >> 6, m2 = i & 63;
        Ast[k2][m2] = sAval(m2, k2);
        Bs[k2][m2] = sBval(k2, m2);
    }
    for (int i = t; i < 64 * 64; i += 256) {
        int r2 = i >> 6, c2 = i & 63;
        Qv[r2][c2] = sQval(r2, c2);
        Kv[r2][c2] = sKval(r2, c2);
    }
    __syncthreads();
    if (s_ok) {
        const int w = t >> 6;
        const int* cl = ctab[t & 63];
        const int am = cl[0], ak2 = cl[1], bn2 = cl[2], bk2 = cl[3], cD = cl[4];
        const int rd[4] = {cl[5], cl[6], cl[7], cl[8]};
        int ok = 1;
        // proj-pattern: D = A(64x32) * B(32x64)
        {
            f64x4 acc4[4] = { {0,0,0,0},{0,0,0,0},{0,0,0,0},{0,0,0,0} };
#pragma unroll
            for (int ks = 0; ks < 8; ks++) {
                double ad = (double)Ast[4 * ks + ak2][16 * w + am];
#pragma unroll
                for (int nt = 0; nt < 4; nt++) {
                    double bd = (double)Bs[4 * ks + bk2][16 * nt + bn2];
                    acc4[nt] = __builtin_amdgcn_mfma_f64_16x16x4f64(ad, bd, acc4[nt], 0, 0, 0);
                }
            }
#pragma unroll
            for (int nt = 0; nt < 4; nt++)
#pragma unroll
                for (int i = 0; i < 4; i++) {
                    int row = 16 * w + rd[i], col = 16 * nt + cD;
                    double ref = 0.0;
                    for (int k2 = 0; k2 < 32; k2++)
                        ref += (double)sAval(row, k2) * (double)sBval(k2, col);
                    if (acc4[nt][i] != ref) ok = 0;
                }
        }
        // attn-pattern: S = Q(16-strip) K^T with K staged [c][k]
        {
            double aqv[16];
#pragma unroll
            for (int ks = 0; ks < 16; ks++)
                aqv[ks] = (double)Qv[16 * w + am][4 * ks + ak2];
            f64x4 S[4] = { {0,0,0,0},{0,0,0,0},{0,0,0,0},{0,0,0,0} };
#pragma unroll
            for (int ks = 0; ks < 16; ks++) {
#pragma unroll
                for (int nt = 0; nt < 4; nt++) {
                    double bd = (double)Kv[16 * nt + bn2][4 * ks + bk2];
                    S[nt] = __builtin_amdgcn_mfma_f64_16x16x4f64(aqv[ks], bd, S[nt], 0, 0, 0);
                }
            }
#pragma unroll
            for (int nt = 0; nt < 4; nt++)
#pragma unroll
                for (int i = 0; i < 4; i++) {
                    int row = 16 * w + rd[i], col = 16 * nt + cD;
                    double ref = 0.0;
                    for (int k2 = 0; k2 < 64; k2++)
                        ref += (double)sQval(row, k2) * (double)sKval(col, k2);
                    if (S[nt][i] != ref) ok = 0;
                }
        }
        if (!ok) s_bad = 1;
    }
    __syncthreads();
    if (t < 64) {
#pragma unroll
        for (int j = 0; j < 12; j++) cal[16 + t * 12 + j] = ctab[t][j];
    }
    if (t == 0) {
        cal[0] = (s_ok && !s_bad) ? 1 : 0;
        cal[1] = (s_ok && !s_bad && s_std) ? 1 : 0;
    }
#else
    if (threadIdx.x == 0) { cal[0] = 0; cal[1] = 0; }
#endif
}

// ---------------------------------------------------------------------------
// V pre-transpose: vv [bh][c][v] fp32 -> hi/lo bf16 split, layout [bh][v][C].
// Memory-bound one-shot pass (~15 us); lets attention stage V tiles as
// straight 16B copies with B-fragment-ready rows (contiguous in keys c).
// ---------------------------------------------------------------------------
__global__ __launch_bounds__(256) void v_to_bf16t(
    const float* __restrict__ vv, u16* __restrict__ hi, u16* __restrict__ lo)
{
    __shared__ float Ls[64][65];
    const int bh = blockIdx.y, c0 = blockIdx.x * 64;
    const int t = threadIdx.x;
    const int c = t >> 2, vb = (t & 3) * 16;
    const float* src = vv + ((size_t)bh * C_ + c0 + c) * KV_ + vb;
#pragma unroll
    for (int i = 0; i < 4; i++) {
        float4 p = *(const float4*)(src + 4 * i);
        Ls[vb + 4*i + 0][c] = p.x;
        Ls[vb + 4*i + 1][c] = p.y;
        Ls[vb + 4*i + 2][c] = p.z;
        Ls[vb + 4*i + 3][c] = p.w;
    }
    __syncthreads();
#pragma unroll
    for (int it = 0; it < 2; it++) {
        int idx = t + 256 * it;            // 0..511 : 64 rows x 8 chunks
        int v = idx >> 3, ch = idx & 7;
        u16 h8[8], l8[8];
#pragma unroll
        for (int j = 0; j < 8; j++) {
            float x = Ls[v][ch * 8 + j];
            h8[j] = f2bf(x);
            l8[j] = f2bf(x - bf2f(h8[j]));
        }
        size_t off = ((size_t)bh * KV_ + v) * C_ + c0 + ch * 8;
        int4 hp, lp;
        hp.x = (int)((unsigned)h8[0] | ((unsigned)h8[1] << 16));
        hp.y = (int)((unsigned)h8[2] | ((unsigned)h8[3] << 16));
        hp.z = (int)((unsigned)h8[4] | ((unsigned)h8[5] << 16));
        hp.w = (int)((unsigned)h8[6] | ((unsigned)h8[7] << 16));
        lp.x = (int)((unsigned)l8[0] | ((unsigned)l8[1] << 16));
        lp.y = (int)((unsigned)l8[2] | ((unsigned)l8[3] << 16));
        lp.z = (int)((unsigned)l8[4] | ((unsigned)l8[5] << 16));
        lp.w = (int)((unsigned)l8[6] | ((unsigned)l8[7] << 16));
        *(int4*)(hi + off) = hp;
        *(int4*)(lo + off) = lp;
    }
}

// ---------------------------------------------------------------------------
// Q/K projection GEMM: fp64 ACCUMULATION, fp32 LDS tiles. (round-2, passing)
// ---------------------------------------------------------------------------
template<int AMODE>
__global__ __launch_bounds__(256) void proj_qk64(
    const void* __restrict__ Ab, const void* __restrict__ Bb,
    float* __restrict__ Cb, const int* __restrict__ flags,
    const int* __restrict__ cal,
    int N, int Kd, long long a_bstr, long long b_hstr, long long c_zstr, int NH)
{
    const int isf = flags[0];
    const int isfA = (AMODE == 1) ? 1 : isf;
    __shared__ float Ast[32][65];   // [k][m]
    __shared__ float Bs[32][65];    // [k][n]
    const int t = threadIdx.x;
    const int m0 = blockIdx.x * 64, n0 = blockIdx.y * 64;
    const int zb = blockIdx.z / NH, zh = blockIdx.z % NH;
    const size_t aoff = (size_t)zb * a_bstr, boff = (size_t)zh * b_hstr;
    const size_t czoff = (size_t)blockIdx.z * c_zstr;
    const int ar = t >> 2, ak = (t & 3) * 8;
    const int bk = t >> 3, bn = (t & 7) * 8;
    const int cok = cal[0];

#if HAVE_MFMA64
    if (cok) {
        const int* cl = cal + 16 + (t & 63) * 12;
        const int am = cl[0], ak2 = cl[1], bn2 = cl[2], bk2 = cl[3], cD = cl[4];
        const int rd[4] = {cl[5], cl[6], cl[7], cl[8]};
        const int w = t >> 6;
        f64x4 acc4[4] = { {0,0,0,0},{0,0,0,0},{0,0,0,0},{0,0,0,0} };
        for (int k0 = 0; k0 < Kd; k0 += 32) {
            float av[8];
            {
                size_t off = aoff + (size_t)(m0 + ar) * Kd + k0 + ak;
                if (isfA) {
                    const float* ap = (const float*)Ab + off;
                    float4 p0 = *(const float4*)ap, p1 = *((const float4*)ap + 1);
                    av[0]=p0.x; av[1]=p0.y; av[2]=p0.z; av[3]=p0.w;
                    av[4]=p1.x; av[5]=p1.y; av[6]=p1.z; av[7]=p1.w;
                } else {
                    const u16* ap = (const u16*)Ab + off;
                    int4 p = *(const int4*)ap;
                    unsigned int u[4] = {(unsigned)p.x,(unsigned)p.y,(unsigned)p.z,(unsigned)p.w};
#pragma unroll
                    for (int j = 0; j < 4; j++) {
                        av[2*j]   = bf2f((u16)(u[j] & 0xffffu));
                        av[2*j+1] = bf2f((u16)(u[j] >> 16));
                    }
                }
            }
#pragma unroll
            for (int j = 0; j < 8; j++) Ast[ak + j][ar] = av[j];
            float bv[8];
            {
                size_t off = boff + (size_t)(k0 + bk) * N + n0 + bn;
                if (isf) {
                    const float* bp = (const float*)Bb + off;
                    float4 p0 = *(const float4*)bp, p1 = *((const float4*)bp + 1);
                    bv[0]=p0.x; bv[1]=p0.y; bv[2]=p0.z; bv[3]=p0.w;
                    bv[4]=p1.x; bv[5]=p1.y; bv[6]=p1.z; bv[7]=p1.w;
                } else {
                    const u16* bp = (const u16*)Bb + off;
                    int4 p = *(const int4*)bp;
                    unsigned int u[4] = {(unsigned)p.x,(unsigned)p.y,(unsigned)p.z,(unsigned)p.w};
#pragma unroll
                    for (int j = 0; j < 4; j++) {
                        bv[2*j]   = bf2f((u16)(u[j] & 0xffffu));
                        bv[2*j+1] = bf2f((u16)(u[j] >> 16));
                    }
                }
            }
#pragma unroll
            for (int j = 0; j < 8; j++) Bs[bk][bn + j] = bv[j];
            __syncthreads();
#pragma unroll
            for (int ks = 0; ks < 8; ks++) {
                double ad = (double)Ast[4 * ks + ak2][16 * w + am];
#pragma unroll
                for (int nt = 0; nt < 4; nt++) {
                    double bd = (double)Bs[4 * ks + bk2][16 * nt + bn2];
                    acc4[nt] = __builtin_amdgcn_mfma_f64_16x16x4f64(ad, bd, acc4[nt], 0, 0, 0);
                }
            }
            __syncthreads();
        }
#pragma unroll
        for (int nt = 0; nt < 4; nt++)
#pragma unroll
            for (int i = 0; i < 4; i++)
                Cb[czoff + (size_t)(m0 + 16 * w + rd[i]) * N + n0 + 16 * nt + cD] =
                    (float)acc4[nt][i];
        return;
    }
#endif
    // ---- legacy scalar-fp64 path (round-0, passing) ----
    double acc[4][4] = {};
    for (int k0 = 0; k0 < Kd; k0 += 32) {
        float av[8];
        {
            size_t off = aoff + (size_t)(m0 + ar) * Kd + k0 + ak;
            if (isfA) {
                const float* ap = (const float*)Ab + off;
                float4 p0 = *(const float4*)ap, p1 = *((const float4*)ap + 1);
                av[0]=p0.x; av[1]=p0.y; av[2]=p0.z; av[3]=p0.w;
                av[4]=p1.x; av[5]=p1.y; av[6]=p1.z; av[7]=p1.w;
            } else {
                const u16* ap = (const u16*)Ab + off;
                int4 p = *(const int4*)ap;
                unsigned int u[4] = {(unsigned)p.x,(unsigned)p.y,(unsigned)p.z,(unsigned)p.w};
#pragma unroll
                for (int j = 0; j < 4; j++) {
                    av[2*j]   = bf2f((u16)(u[j] & 0xffffu));
                    av[2*j+1] = bf2f((u16)(u[j] >> 16));
                }
            }
        }
#pragma unroll
        for (int j = 0; j < 8; j++) Ast[ak + j][ar] = av[j];
        float bv[8];
        {
            size_t off = boff + (size_t)(k0 + bk) * N + n0 + bn;
            if (isf) {
                const float* bp = (const float*)Bb + off;
                float4 p0 = *(const float4*)bp, p1 = *((const float4*)bp + 1);
                bv[0]=p0.x; bv[1]=p0.y; bv[2]=p0.z; bv[3]=p0.w;
                bv[4]=p1.x; bv[5]=p1.y; bv[6]=p1.z; bv[7]=p1.w;
            } else {
                const u16* bp = (const u16*)Bb + off;
                int4 p = *(const int4*)bp;
                unsigned int u[4] = {(unsigned)p.x,(unsigned)p.y,(unsigned)p.z,(unsigned)p.w};
#pragma unroll
                for (int j = 0; j < 4; j++) {
                    bv[2*j]   = bf2f((u16)(u[j] & 0xffffu));
                    bv[2*j+1] = bf2f((u16)(u[j] >> 16));
                }
            }
        }
#pragma unroll
        for (int j = 0; j < 8; j++) Bs[bk][bn + j] = bv[j];
        __syncthreads();
        const int r0 = (t & 15) * 4, c0 = (t >> 4) * 4;
#pragma unroll
        for (int kk = 0; kk < 32; kk++) {
            float4 a4 = *(const float4*)&Ast[kk][r0];
            float4 b4 = *(const float4*)&Bs[kk][c0];
            double a0=a4.x, a1=a4.y, a2=a4.z, a3=a4.w;
            double b0=b4.x, b1=b4.y, b2=b4.z, b3=b4.w;
            acc[0][0] += a0*b0; acc[0][1] += a0*b1; acc[0][2] += a0*b2; acc[0][3] += a0*b3;
            acc[1][0] += a1*b0; acc[1][1] += a1*b1; acc[1][2] += a1*b2; acc[1][3] += a1*b3;
            acc[2][0] += a2*b0; acc[2][1] += a2*b1; acc[2][2] += a2*b2; acc[2][3] += a2*b3;
            acc[3][0] += a3*b0; acc[3][1] += a3*b1; acc[3][2] += a3*b2; acc[3][3] += a3*b3;
        }
        __syncthreads();
    }
    {
        const int r0 = (t & 15) * 4, c0 = (t >> 4) * 4;
#pragma unroll
        for (int i = 0; i < 4; i++)
#pragma unroll
            for (int j = 0; j < 4; j++)
                Cb[czoff + (size_t)(m0 + r0 + i) * N + n0 + c0 + j] = (float)acc[i][j];
    }
}

// ---------------------------------------------------------------------------
// MFMA GEMM with bf16 hi/lo 3-term split (post-softmax ops). Unchanged.
// ---------------------------------------------------------------------------
template<int AMODE, bool RELU, bool BIAS>
__global__ __launch_bounds__(256) void gemm_hilo(
    const void* __restrict__ Ab, const void* __restrict__ Bb,
    float* __restrict__ Cb, const void* __restrict__ bias,
    const int* __restrict__ flags,
    int N, int Kd, long long a_bstr, long long b_hstr, long long c_zstr, int NH)
{
    const int isf = flags[0];
    const int aIsF32 = (AMODE == 1) ? 1 : isf;
    __shared__ u16 a_hi[64][40], a_lo[64][40];
    __shared__ u16 b_hi[64][40], b_lo[64][40];

    const int tid = threadIdx.x;
    const int w = tid >> 6, l = tid & 63;
    const int lq = l & 15, quad = l >> 4;
    const int m0 = blockIdx.x * 64, n0 = blockIdx.y * 64;
    const int zb = blockIdx.z / NH, zh = blockIdx.z % NH;
    const size_t aoff = (size_t)zb * a_bstr, boff = (size_t)zh * b_hstr;

    f32x4 acc[4] = { {0,0,0,0},{0,0,0,0},{0,0,0,0},{0,0,0,0} };
    const int arow = tid >> 2, ac8 = (tid & 3) * 8;
    const int bk = tid >> 3, bn8 = (tid & 7) * 8;

    for (int k0 = 0; k0 < Kd; k0 += 32) {
        {
            size_t off = aoff + (size_t)(m0 + arow) * Kd + k0 + ac8;
            u16 hh[8], ll[8];
            if (aIsF32) {
                const float* ap = (const float*)Ab + off;
                float4 p0 = *(const float4*)ap, p1 = *((const float4*)ap + 1);
                float vv[8] = {p0.x,p0.y,p0.z,p0.w,p1.x,p1.y,p1.z,p1.w};
#pragma unroll
                for (int j = 0; j < 8; j++) {
                    hh[j] = f2bf(vv[j]);
                    ll[j] = f2bf(vv[j] - bf2f(hh[j]));
                }
            } else {
                int4 p = *(const int4*)((const u16*)Ab + off);
                unsigned int u[4] = {(unsigned)p.x,(unsigned)p.y,(unsigned)p.z,(unsigned)p.w};
#pragma unroll
                for (int j = 0; j < 4; j++) {
                    hh[2*j]   = (u16)(u[j] & 0xffffu);
                    hh[2*j+1] = (u16)(u[j] >> 16);
                    ll[2*j] = 0; ll[2*j+1] = 0;
                }
            }
            int4 ph, pl;
            ph.x = (int)((unsigned)hh[0] | ((unsigned)hh[1] << 16));
            ph.y = (int)((unsigned)hh[2] | ((unsigned)hh[3] << 16));
            ph.z = (int)((unsigned)hh[4] | ((unsigned)hh[5] << 16));
            ph.w = (int)((unsigned)hh[6] | ((unsigned)hh[7] << 16));
            pl.x = (int)((unsigned)ll[0] | ((unsigned)ll[1] << 16));
            pl.y = (int)((unsigned)ll[2] | ((unsigned)ll[3] << 16));
            pl.z = (int)((unsigned)ll[4] | ((unsigned)ll[5] << 16));
            pl.w = (int)((unsigned)ll[6] | ((unsigned)ll[7] << 16));
            *(int4*)&a_hi[arow][ac8] = ph;
            *(int4*)&a_lo[arow][ac8] = pl;
        }
        {
            size_t off = boff + (size_t)(k0 + bk) * N + n0 + bn8;
            u16 hh[8], ll[8];
            if (isf) {
                const float* bp = (const float*)Bb + off;
                float4 p0 = *(const float4*)bp, p1 = *((const float4*)bp + 1);
                float vv[8] = {p0.x,p0.y,p0.z,p0.w,p1.x,p1.y,p1.z,p1.w};
#pragma unroll
                for (int j = 0; j < 8; j++) {
                    hh[j] = f2bf(vv[j]);
                    ll[j] = f2bf(vv[j] - bf2f(hh[j]));
                }
            } else {
                int4 p = *(const int4*)((const u16*)Bb + off);
                unsigned int u[4] = {(unsigned)p.x,(unsigned)p.y,(unsigned)p.z,(unsigned)p.w};
#pragma unroll
                for (int j = 0; j < 4; j++) {
                    hh[2*j]   = (u16)(u[j] & 0xffffu);
                    hh[2*j+1] = (u16)(u[j] >> 16);
                    ll[2*j] = 0; ll[2*j+1] = 0;
                }
            }
#pragma unroll
            for (int j = 0; j < 8; j++) {
                b_hi[bn8 + j][bk] = hh[j];
                b_lo[bn8 + j][bk] = ll[j];
            }
        }
        __syncthreads();
        bf16x8 ah = *(bf16x8*)&a_hi[w * 16 + lq][quad * 8];
        bf16x8 al = *(bf16x8*)&a_lo[w * 16 + lq][quad * 8];
#pragma unroll
        for (int nt = 0; nt < 4; nt++) {
            bf16x8 bh = *(bf16x8*)&b_hi[nt * 16 + lq][quad * 8];
            bf16x8 bl = *(bf16x8*)&b_lo[nt * 16 + lq][quad * 8];
            acc[nt] = __builtin_amdgcn_mfma_f32_16x16x32_bf16(ah, bh, acc[nt], 0, 0, 0);
            acc[nt] = __builtin_amdgcn_mfma_f32_16x16x32_bf16(ah, bl, acc[nt], 0, 0, 0);
            acc[nt] = __builtin_amdgcn_mfma_f32_16x16x32_bf16(al, bh, acc[nt], 0, 0, 0);
        }
        __syncthreads();
    }

    const int rowb = m0 + w * 16 + quad * 4;
    const size_t czoff = (size_t)blockIdx.z * c_zstr;
#pragma unroll
    for (int nt = 0; nt < 4; nt++) {
        int col = n0 + nt * 16 + lq;
        float bv = BIAS ? ldflag(bias, col, isf) : 0.0f;
#pragma unroll
        for (int r = 0; r < 4; r++) {
            float val = acc[nt][r] + bv;
            if (RELU) val = fmaxf(val, 0.0f);
            Cb[czoff + (size_t)(rowb + r) * N + col] = val;
        }
    }
}

// ---------------------------------------------------------------------------
// Flash-style attention, fp64 logits.
// cal[0]&&cal[1] (standard layout) -> QK^T on f64 matrix pipe + PV on the
//   bf16 matrix pipe (hi/lo 3-term MFMA; P written bf16 hi/lo to a
//   wave-private LDS slab in A-frag layout [q][c]; V tiles staged from the
//   pre-transposed global Vt arrays, B-frag-ready). The f64 D-layout ==
//   bf16 D-layout, so m/l/alpha state and the accumulators share the same
//   per-lane row mapping 4g+i.  LDS reuse: K tile -> Qs, Vt -> KPs, P -> Vs.
// cal[0]&&!cal[1] -> round-2 generic table-driven path (verbatim).
// else -> round-0 scalar path (verbatim).
// Mask quirk faithful: -100 on UNSCALED fp64 logit when key <= query.
// ---------------------------------------------------------------------------
__global__ __launch_bounds__(256) void attn_flash(
    const float* __restrict__ q, const float* __restrict__ k,
    const float* __restrict__ v,
    const u16* __restrict__ vthi, const u16* __restrict__ vtlo,
    float* __restrict__ pre,
    const int* __restrict__ cal, int masked)
{
    __shared__ float Qs[64][68];    // legacy: Q^T | fast: Q, then K tile [c][k]
    __shared__ float KPs[64][68];   // legacy: K^T then P | fastPV: Vt hi/lo (u16)
    __shared__ float Vs[64][68];    // legacy/generic: V tile | fastPV: P slabs (u16)
    __shared__ float redm[64][17];
    __shared__ float redl[64][17];
    __shared__ float mrow[64], lrow[64], arow[64];

    const int idx = blockIdx.x;
    const int q0 = (idx & (C_ / 64 - 1)) * 64;
    const int h = (idx >> 5) & (H_ - 1);
    const int b = idx >> 9;
    const size_t bh = (size_t)(b * H_ + h);
    const float* Qg = q + (bh * C_ + q0) * KV_;
    const float* Kg = k + bh * C_ * KV_;
    const float* Vg = v + bh * C_ * KV_;
    const int t = threadIdx.x;
    const int cok = cal[0];
    const int cstd = cal[1];

#if HAVE_MFMA64
    if (cok && cstd) {
        // ---------------- fast path: f64 QK^T + bf16-MFMA PV ----------------
        const int w = t >> 6, l15 = t & 15, g = (t >> 4) & 3;
        const int srow = t >> 2, sc = (t & 3) * 16;
        u16* VtH = (u16*)&KPs[0][0];          // [64][68] u16
        u16* VtL = VtH + 64 * 68;
        u16* PH = (u16*)&Vs[0][0] + w * 2176; // per-wave [16][68] u16
        u16* PL = PH + 1088;
        const u16* vthg = vthi + bh * (size_t)KV_ * C_;
        const u16* vtlg = vtlo + bh * (size_t)KV_ * C_;

        {   // stage Q [q][k]
            const float* src = Qg + (size_t)srow * KV_ + sc;
#pragma unroll
            for (int i = 0; i < 4; i++)
                *(float4*)&Qs[srow][sc + 4 * i] = *(const float4*)(src + 4 * i);
        }
        __syncthreads();
        double aq[16];
#pragma unroll
        for (int ks = 0; ks < 16; ks++)
            aq[ks] = (double)Qs[16 * w + l15][4 * ks + g];

        f32x4 acc[4] = { {0,0,0,0},{0,0,0,0},{0,0,0,0},{0,0,0,0} };
        float mreg[4] = {-3.0e38f, -3.0e38f, -3.0e38f, -3.0e38f};
        float lreg[4] = {0.0f, 0.0f, 0.0f, 0.0f};

        for (int kt = 0; kt < 32; kt++) {
            const int c0 = kt * 64;
            __syncthreads();   // prev tile fully consumed (incl. PV reads)
            {   // stage K fp32 [c][k] into Qs region
                const float* ksrc = Kg + (size_t)(c0 + srow) * KV_ + sc;
#pragma unroll
                for (int i = 0; i < 4; i++)
                    *(float4*)&Qs[srow][sc + 4 * i] = *(const float4*)(ksrc + 4 * i);
            }
            // stage Vt hi/lo tiles: 1024 x 16B chunks, B-frag-ready rows
#pragma unroll
            for (int it = 0; it < 4; it++) {
                int idx2 = t + 256 * it;
                int arr = idx2 >> 9, rem = idx2 & 511;
                int vrow = rem >> 3, ch = rem & 7;
                const u16* gsrc = (arr ? vtlg : vthg) + (size_t)vrow * C_ + c0 + ch * 8;
                u16* dst = (arr ? VtL : VtH) + 68 * vrow + 8 * ch;
                int4 d = *(const int4*)gsrc;
                *(int2*)dst = make_int2(d.x, d.y);
                *(int2*)(dst + 4) = make_int2(d.z, d.w);
            }
            __syncthreads();

            // S strip (16 q x 64 keys) in fp64 on the matrix pipe
            f64x4 S[4] = { {0,0,0,0},{0,0,0,0},{0,0,0,0},{0,0,0,0} };
#pragma unroll
            for (int ks = 0; ks < 16; ks++) {
#pragma unroll
                for (int nt = 0; nt < 4; nt++) {
                    double bd = (double)Qs[16 * nt + l15][4 * ks + g];
                    S[nt] = __builtin_amdgcn_mfma_f64_16x16x4f64(aq[ks], bd, S[nt], 0, 0, 0);
                }
            }
            if (masked) {
#pragma unroll
                for (int nt = 0; nt < 4; nt++) {
                    const int cg = c0 + 16 * nt + l15;
#pragma unroll
                    for (int i = 0; i < 4; i++)
                        if (cg <= q0 + 16 * w + 4 * g + i) S[nt][i] -= 100.0;
                }
            }
            // wave-local online softmax (rows 4g+i, uniform per 16-lane group)
            float tm[4];
#pragma unroll
            for (int i = 0; i < 4; i++)
                tm[i] = fmaxf(fmaxf((float)S[0][i], (float)S[1][i]),
                              fmaxf((float)S[2][i], (float)S[3][i]));
#pragma unroll
            for (int off = 1; off < 16; off <<= 1)
#pragma unroll
                for (int i = 0; i < 4; i++)
                    tm[i] = fmaxf(tm[i], __shfl_xor(tm[i], off, 64));
            float alpha[4];
#pragma unroll
            for (int i = 0; i < 4; i++) {
                const float mo = mreg[i];
                const float mn = fmaxf(mo, tm[i]);
                alpha[i] = (mo < -1.0e37f) ? 0.0f : __expf(0.125f * (mo - mn));
                mreg[i] = mn;
            }
            // P = exp(0.125(S-m)) -> bf16 hi/lo into wave-private slab [q][c]
            float ts[4] = {0.0f, 0.0f, 0.0f, 0.0f};
#pragma unroll
            for (int nt = 0; nt < 4; nt++) {
#pragma unroll
                for (int i = 0; i < 4; i++) {
                    float p = __expf((float)(0.125 * (S[nt][i] - (double)mreg[i])));
                    ts[i] += p;
                    u16 ph = f2bf(p);
                    u16 pl = f2bf(p - bf2f(ph));
                    PH[68 * (4 * g + i) + 16 * nt + l15] = ph;
                    PL[68 * (4 * g + i) + 16 * nt + l15] = pl;
                }
            }
#pragma unroll
            for (int off = 1; off < 16; off <<= 1)
#pragma unroll
                for (int i = 0; i < 4; i++)
                    ts[i] += __shfl_xor(ts[i], off, 64);
#pragma unroll
            for (int i = 0; i < 4; i++) {
                lreg[i] = lreg[i] * alpha[i] + ts[i];
#pragma unroll
                for (int nt = 0; nt < 4; nt++) acc[nt][i] *= alpha[i];
            }
            // wave-internal LDS write->read fence (cross-lane, same wave)
            __builtin_amdgcn_sched_barrier(0);
            asm volatile("s_waitcnt lgkmcnt(0)" ::: "memory");
            __builtin_amdgcn_sched_barrier(0);
            // PV on the bf16 matrix pipe: 3-term hi/lo, K=32 x 2 steps
            union F8 { struct { int2 a, b; } p; bf16x8 v; };
#pragma unroll
            for (int ks2 = 0; ks2 < 2; ks2++) {
                const u16* pa = PH + 68 * l15 + 8 * g + 32 * ks2;
                const u16* pb = PL + 68 * l15 + 8 * g + 32 * ks2;
                F8 pah, pal;
                pah.p.a = *(const int2*)pa; pah.p.b = *(const int2*)(pa + 4);
                pal.p.a = *(const int2*)pb; pal.p.b = *(const int2*)(pb + 4);
#pragma unroll
                for (int nt = 0; nt < 4; nt++) {
                    const u16* vh = VtH + 68 * (16 * nt + l15) + 8 * g + 32 * ks2;
                    const u16* vl = VtL + 68 * (16 * nt + l15) + 8 * g + 32 * ks2;
                    F8 vbh, vbl;
                    vbh.p.a = *(const int2*)vh; vbh.p.b = *(const int2*)(vh + 4);
                    vbl.p.a = *(const int2*)vl; vbl.p.b = *(const int2*)(vl + 4);
                    acc[nt] = __builtin_amdgcn_mfma_f32_16x16x32_bf16(pah.v, vbh.v, acc[nt], 0, 0, 0);
                    acc[nt] = __builtin_amdgcn_mfma_f32_16x16x32_bf16(pah.v, vbl.v, acc[nt], 0, 0, 0);
                    acc[nt] = __builtin_amdgcn_mfma_f32_16x16x32_bf16(pal.v, vbh.v, acc[nt], 0, 0, 0);
                }
            }
        }
        // epilogue: out = O / l; pre layout [B, C, H, V]; cols 16nt+l15
#pragma unroll
        for (int i = 0; i < 4; i++) {
            const float li = lreg[i];
            const size_t rbase = (((size_t)b * C_ + q0 + 16 * w + 4 * g + i) * H_ + h) * KV_;
#pragma unroll
            for (int nt = 0; nt < 4; nt++)
                pre[rbase + 16 * nt + l15] = acc[nt][i] / li;
        }
        return;
    }
    if (cok) {
        // ---------------- generic table-driven path (round-2, passing) -----
        const int* cl = cal + 16 + (t & 63) * 12;
        const int am = cl[0], ak2 = cl[1], bn2 = cl[2], bk2 = cl[3], cD = cl[4];
        const int rd[4] = {cl[5], cl[6], cl[7], cl[8]};
        const int w = t >> 6, l15 = t & 15;
        const int srow = t >> 2, sc = (t & 3) * 16;

        {   // stage Q [q][k]
            const float* src = Qg + (size_t)srow * KV_ + sc;
#pragma unroll
            for (int i = 0; i < 4; i++)
                *(float4*)&Qs[srow][sc + 4 * i] = *(const float4*)(src + 4 * i);
        }
        __syncthreads();
        double aq[16];
#pragma unroll
        for (int ks = 0; ks < 16; ks++)
            aq[ks] = (double)Qs[16 * w + am][4 * ks + ak2];

        float O[4][4] = {};
        float mreg[4] = {-3.0e38f, -3.0e38f, -3.0e38f, -3.0e38f};
        float lreg[4] = {0.0f, 0.0f, 0.0f, 0.0f};

        for (int kt = 0; kt < 32; kt++) {
            const int c0 = kt * 64;
            __syncthreads();
            {
                const float* ksrc = Kg + (size_t)(c0 + srow) * KV_ + sc;
                const float* vsrc = Vg + (size_t)(c0 + srow) * KV_ + sc;
#pragma unroll
                for (int i = 0; i < 4; i++) {
                    *(float4*)&Qs[srow][sc + 4 * i] = *(const float4*)(ksrc + 4 * i);
                    *(float4*)&Vs[srow][sc + 4 * i] = *(const float4*)(vsrc + 4 * i);
                }
            }
            __syncthreads();

            f64x4 S[4] = { {0,0,0,0},{0,0,0,0},{0,0,0,0},{0,0,0,0} };
#pragma unroll
            for (int ks = 0; ks < 16; ks++) {
#pragma unroll
                for (int nt = 0; nt < 4; nt++) {
                    double bd = (double)Qs[16 * nt + bn2][4 * ks + bk2];
                    S[nt] = __builtin_amdgcn_mfma_f64_16x16x4f64(aq[ks], bd, S[nt], 0, 0, 0);
                }
            }
            if (masked) {
#pragma unroll
                for (int nt = 0; nt < 4; nt++) {
                    const int cg = c0 + 16 * nt + cD;
#pragma unroll
                    for (int i = 0; i < 4; i++)
                        if (cg <= q0 + 16 * w + rd[i]) S[nt][i] -= 100.0;
                }
            }
            float tm[4];
#pragma unroll
            for (int i = 0; i < 4; i++)
                tm[i] = fmaxf(fmaxf((float)S[0][i], (float)S[1][i]),
                              fmaxf((float)S[2][i], (float)S[3][i]));
#pragma unroll
            for (int off = 1; off < 16; off <<= 1)
#pragma unroll
                for (int i = 0; i < 4; i++)
                    tm[i] = fmaxf(tm[i], __shfl_xor(tm[i], off, 64));
            float alpha[4];
#pragma unroll
            for (int i = 0; i < 4; i++) {
                const float mo = mreg[i];
                const float mn = fmaxf(mo, tm[i]);
                alpha[i] = (mo < -1.0e37f) ? 0.0f : __expf(0.125f * (mo - mn));
                mreg[i] = mn;
            }
            float ts[4] = {0.0f, 0.0f, 0.0f, 0.0f};
#pragma unroll
            for (int nt = 0; nt < 4; nt++) {
                float p0 = __expf((float)(0.125 * (S[nt][0] - (double)mreg[0])));
                float p1 = __expf((float)(0.125 * (S[nt][1] - (double)mreg[1])));
                float p2 = __expf((float)(0.125 * (S[nt][2] - (double)mreg[2])));
                float p3 = __expf((float)(0.125 * (S[nt][3] - (double)mreg[3])));
                ts[0] += p0; ts[1] += p1; ts[2] += p2; ts[3] += p3;
                KPs[16 * nt + cD][17 * w + rd[0]] = p0;
                KPs[16 * nt + cD][17 * w + rd[1]] = p1;
                KPs[16 * nt + cD][17 * w + rd[2]] = p2;
                KPs[16 * nt + cD][17 * w + rd[3]] = p3;
            }
#pragma unroll
            for (int off = 1; off < 16; off <<= 1)
#pragma unroll
                for (int i = 0; i < 4; i++)
                    ts[i] += __shfl_xor(ts[i], off, 64);
#pragma unroll
            for (int i = 0; i < 4; i++) {
                lreg[i] = lreg[i] * alpha[i] + ts[i];
#pragma unroll
                for (int j = 0; j < 4; j++) O[i][j] *= alpha[i];
            }
#pragma unroll 4
            for (int c = 0; c < 64; c++) {
                const float pd0 = KPs[c][17 * w + rd[0]];
                const float pd1 = KPs[c][17 * w + rd[1]];
                const float pd2 = KPs[c][17 * w + rd[2]];
                const float pd3 = KPs[c][17 * w + rd[3]];
                float4 vb = *(const float4*)&Vs[c][4 * l15];
                const float vd[4] = {vb.x, vb.y, vb.z, vb.w};
#pragma unroll
                for (int j = 0; j < 4; j++) {
                    O[0][j] += pd0 * vd[j];
                    O[1][j] += pd1 * vd[j];
                    O[2][j] += pd2 * vd[j];
                    O[3][j] += pd3 * vd[j];
                }
            }
        }
#pragma unroll
        for (int i = 0; i < 4; i++) {
            const float li = lreg[i];
            float4 o4;
            o4.x = O[i][0] / li; o4.y = O[i][1] / li;
            o4.z = O[i][2] / li; o4.w = O[i][3] / li;
            *(float4*)&pre[(((size_t)b * C_ + q0 + 16 * w + rd[i]) * H_ + h) * KV_ + 4 * l15] = o4;
        }
        return;
    }
#endif
    // ---- legacy scalar-fp64 path (round-0, passing) ----
    {
        const int tq = t & 15, tc = t >> 4;
        const int srow = t >> 2, scol = (t & 3) * 16;
        {
            const float* src = Qg + (size_t)srow * KV_ + scol;
#pragma unroll
            for (int i = 0; i < 4; i++) {
                float4 p4 = *(const float4*)(src + 4 * i);
                Qs[scol + 4*i + 0][srow] = p4.x;
                Qs[scol + 4*i + 1][srow] = p4.y;
                Qs[scol + 4*i + 2][srow] = p4.z;
                Qs[scol + 4*i + 3][srow] = p4.w;
            }
        }
        if (t < 64) { mrow[t] = -3.0e38f; lrow[t] = 0.0f; }

        float O[4][4] = {};

        for (int kt = 0; kt < 32; kt++) {
            const int c0 = kt * 64;
            __syncthreads();
            {
                const float* ksrc = Kg + (size_t)(c0 + srow) * KV_ + scol;
#pragma unroll
                for (int i = 0; i < 4; i++) {
                    float4 p4 = *(const float4*)(ksrc + 4 * i);
                    KPs[scol + 4*i + 0][srow] = p4.x;
                    KPs[scol + 4*i + 1][srow] = p4.y;
                    KPs[scol + 4*i + 2][srow] = p4.z;
                    KPs[scol + 4*i + 3][srow] = p4.w;
                }
                const float* vsrc = Vg + (size_t)(c0 + srow) * KV_ + scol;
#pragma unroll
                for (int i = 0; i < 4; i++)
                    *(float4*)&Vs[srow][scol + 4 * i] = *(const float4*)(vsrc + 4 * i);
            }
            __syncthreads();

            double Sd[4][4] = {};
#pragma unroll 4
            for (int j = 0; j < 64; j++) {
                float4 qa = *(const float4*)&Qs[j][4 * tq];
                float4 kb = *(const float4*)&KPs[j][4 * tc];
                double qd[4] = {qa.x, qa.y, qa.z, qa.w};
                double kd[4] = {kb.x, kb.y, kb.z, kb.w};
#pragma unroll
                for (int i = 0; i < 4; i++)
#pragma unroll
                    for (int jj = 0; jj < 4; jj++)
                        Sd[i][jj] += qd[i] * kd[jj];
            }
            if (masked) {
#pragma unroll
                for (int i = 0; i < 4; i++)
#pragma unroll
                    for (int jj = 0; jj < 4; jj++)
                        if (c0 + 4 * tc + jj <= q0 + 4 * tq + i) Sd[i][jj] -= 100.0;
            }
#pragma unroll
            for (int i = 0; i < 4; i++) {
                double mm = fmax(fmax(Sd[i][0], Sd[i][1]), fmax(Sd[i][2], Sd[i][3]));
                redm[4 * tq + i][tc] = (float)mm;
            }
            __syncthreads();
            if (t < 64) {
                float tmv = redm[t][0];
#pragma unroll
                for (int x = 1; x < 16; x++) tmv = fmaxf(tmv, redm[t][x]);
                float mo = mrow[t];
                float mn = fmaxf(mo, tmv);
                arow[t] = (mo < -1.0e37f) ? 0.0f
                           : (float)exp(0.125 * ((double)mo - (double)mn));
                mrow[t] = mn;
            }
            __syncthreads();
#pragma unroll
            for (int i = 0; i < 4; i++) {
                double mn = (double)mrow[4 * tq + i];
                float ls = 0.0f;
#pragma unroll
                for (int jj = 0; jj < 4; jj++) {
                    float p = (float)exp(0.125 * (Sd[i][jj] - mn));
                    KPs[4 * tc + jj][4 * tq + i] = p;
                    ls += p;
                }
                redl[4 * tq + i][tc] = ls;
            }
            __syncthreads();
            if (t < 64) {
                float s = 0.0f;
#pragma unroll
                for (int x = 0; x < 16; x++) s += redl[t][x];
                lrow[t] = lrow[t] * arow[t] + s;
            }
            float al[4];
#pragma unroll
            for (int i = 0; i < 4; i++) al[i] = arow[4 * tq + i];
#pragma unroll
            for (int i = 0; i < 4; i++)
#pragma unroll
                for (int jj = 0; jj < 4; jj++) O[i][jj] *= al[i];
#pragma unroll 4
            for (int c = 0; c < 64; c++) {
                float4 pa = *(const float4*)&KPs[c][4 * tq];
                float4 vb = *(const float4*)&Vs[c][4 * tc];
                float pd[4] = {pa.x, pa.y, pa.z, pa.w};
                float vd[4] = {vb.x, vb.y, vb.z, vb.w};
#pragma unroll
                for (int i = 0; i < 4; i++)
#pragma unroll
                    for (int jj = 0; jj < 4; jj++)
                        O[i][jj] += pd[i] * vd[jj];
            }
        }
        __syncthreads();
#pragma unroll
        for (int i = 0; i < 4; i++) {
            float li = lrow[4 * tq + i];
            float4 o4;
            o4.x = O[i][0] / li; o4.y = O[i][1] / li;
            o4.z = O[i][2] / li; o4.w = O[i][3] / li;
            *(float4*)&pre[(((size_t)b * C_ + q0 + 4 * tq + i) * H_ + h) * KV_ + 4 * tc] = o4;
        }
    }
}

// ---------------------------------------------------------------------------
// Residual + LayerNorm, fp64 stats, fp32 storage. In-place safe. Unchanged.
// ---------------------------------------------------------------------------
template<int IN1MODE, int OUTMODE>
__global__ __launch_bounds__(256) void ln_f64(
    const void* __restrict__ in1, const float* __restrict__ in2,
    const void* __restrict__ g, const void* __restrict__ b,
    void* __restrict__ out, const int* __restrict__ flags)
{
    __shared__ double buf[M_];
    __shared__ double red[4];
    const int isf = flags[0];
    const int row = blockIdx.x;
    const size_t base = (size_t)row * M_;
    const int tid = threadIdx.x;
    double s = 0.0;
    for (int i = tid; i < M_; i += 256) {
        double v1 = (IN1MODE == 1) ? (double)((const float*)in1)[base + i]
                                   : (double)ldflag(in1, base + i, isf);
        double val = v1 + (double)in2[base + i];
        buf[i] = val;
        s += val;
    }
    s = blockReduceSumD(s, red, tid);
    const double mu = s * (1.0 / M_);
    double vs = 0.0;
    for (int i = tid; i < M_; i += 256) { double dd = buf[i] - mu; vs += dd * dd; }
    vs = blockReduceSumD(vs, red, tid);
    const double rstd = 1.0 / sqrt(vs * (1.0 / M_) + 1e-5);
    for (int i = tid; i < M_; i += 256) {
        double y = (buf[i] - mu) * rstd * (double)ldflag(g, i, isf) + (double)ldflag(b, i, isf);
        if (OUTMODE == 0) ((float*)out)[base + i] = (float)y;
        else if (isf)     ((float*)out)[base + i] = (float)y;
        else              ((u16*)out)[base + i] = f2bf((float)y);
    }
}

// ---------------------------------------------------------------------------
extern "C" void kernel_launch(void* const* d_in, const int* in_sizes, int n_in,
                              void* d_out, int out_size, void* d_ws, size_t ws_size,
                              hipStream_t stream)
{
    const void* enc = d_in[0];
    const void* x   = d_in[1];
    const void* wq1 = d_in[2];
    const void* wk1 = d_in[3];
    const void* wv1 = d_in[4];
    const void* wo1 = d_in[5];
    const void* g1  = d_in[6];
    const void* b1  = d_in[7];
    const void* wq2 = d_in[8];
    const void* wk2 = d_in[9];
    const void* wv2 = d_in[10];
    const void* wo2 = d_in[11];
    const void* g2  = d_in[12];
    const void* b2  = d_in[13];
    const void* fw1 = d_in[14];
    const void* fb1 = d_in[15];
    const void* fw2 = d_in[16];
    const void* fb2 = d_in[17];
    const void* g3  = d_in[18];
    const void* b3  = d_in[19];

    int* fl = (int*)d_ws;
    int* cal = fl + 16;                                // [0]=ok, [1]=std, [16..] table
    const size_t NQ = (size_t)B_ * C_ * M_;            // 4,194,304
    // Aliasing as the PASSING rounds:
    // S0: q1/q2 -> h1[0] | S1: k1->attout1->k2->attout2 -> h1[1]
    // S2: v1->v2 -> h1[2] | S3: pre1->pre2 -> h1[3] | S4: n1 -> n2 (in-place)
    // Vt scratch: attn1 -> S4 (dead until ln1), attn2 -> d_out (dead until FFN).
    float* S0 = (float*)((char*)d_ws + 4096);
    float* S1 = S0 + NQ;
    float* S2 = S1 + NQ;
    float* S3 = S2 + NQ;
    float* S4 = S3 + NQ;
    float* q = S0, *kk = S1, *vv = S2, *pre = S3, *attout = S1, *n1 = S4, *n2 = S4;
    float* h1 = S0;                                    // fp32 [4096,4096] = S0..S3
    float* ff = (float*)d_out;
    u16* vt1h = (u16*)S4;                              // 2*16*64*2048 u16 = 8.39MB
    u16* vt1l = vt1h + (size_t)B_ * H_ * KV_ * C_;
    u16* vt2h = (u16*)d_out;
    u16* vt2l = vt2h + (size_t)B_ * H_ * KV_ * C_;

    dim3 blk(256);
    dim3 gproj(C_ / 64, KV_ / 64, B_ * H_);            // (32,1,32)
    dim3 gout(B_ * C_ / 64, M_ / 64, 1);               // (64,16,1)
    dim3 gffn1(B_ * C_ / 64, F_ / 64, 1);              // (64,64,1)
    dim3 gffn2(B_ * C_ / 64, M_ / 64, 1);              // (64,16,1)
    dim3 gattn(B_ * H_ * (C_ / 64));                   // 1024
    dim3 gvt(C_ / 64, B_ * H_);                        // (32,32)
    dim3 gln(B_ * C_);                                 // 4096
    const long long AB = (long long)C_ * M_, BH = (long long)M_ * KV_, CZ = (long long)C_ * KV_;

    detect_dtype<<<1, 256, 0, stream>>>((const unsigned int*)wq1, fl);
    calibrate<<<1, 256, 0, stream>>>(cal);

    // ---- self-attention (masked) ----
    proj_qk64<0><<<gproj, blk, 0, stream>>>(x, wq1, q,  fl, cal, KV_, M_, AB, BH, CZ, H_);
    proj_qk64<0><<<gproj, blk, 0, stream>>>(x, wk1, kk, fl, cal, KV_, M_, AB, BH, CZ, H_);
    gemm_hilo<0,false,false><<<gproj, blk, 0, stream>>>(x, wv1, vv, nullptr, fl, KV_, M_, AB, BH, CZ, H_);
    v_to_bf16t<<<gvt, blk, 0, stream>>>(vv, vt1h, vt1l);
    attn_flash<<<gattn, blk, 0, stream>>>(q, kk, vv, vt1h, vt1l, pre, cal, 1);
    gemm_hilo<1,false,false><<<gout, blk, 0, stream>>>(pre, wo1, attout, nullptr, fl, M_, M_, 0, 0, 0, 1);
    ln_f64<0, 0><<<gln, blk, 0, stream>>>(x, attout, g1, b1, n1, fl);

    // ---- cross-attention ----
    proj_qk64<1><<<gproj, blk, 0, stream>>>(n1, wq2, q,  fl, cal, KV_, M_, AB, BH, CZ, H_);
    proj_qk64<0><<<gproj, blk, 0, stream>>>(enc, wk2, kk, fl, cal, KV_, M_, AB, BH, CZ, H_);
    gemm_hilo<0,false,false><<<gproj, blk, 0, stream>>>(enc, wv2, vv, nullptr, fl, KV_, M_, AB, BH, CZ, H_);
    v_to_bf16t<<<gvt, blk, 0, stream>>>(vv, vt2h, vt2l);
    attn_flash<<<gattn, blk, 0, stream>>>(q, kk, vv, vt2h, vt2l, pre, cal, 0);
    gemm_hilo<1,false,false><<<gout, blk, 0, stream>>>(pre, wo2, attout, nullptr, fl, M_, M_, 0, 0, 0, 1);
    ln_f64<1, 0><<<gln, blk, 0, stream>>>(n1, attout, g2, b2, n2, fl);   // in-place S4

    // ---- FFN (h1 fp32 spans S0..S3; ff in d_out; LN3 in-place) ----
    gemm_hilo<1,true,true><<<gffn1, blk, 0, stream>>>(n2, fw1, h1, fb1, fl, F_, M_, 0, 0, 0, 1);
    gemm_hilo<1,false,true><<<gffn2, blk, 0, stream>>>(h1, fw2, ff, fb2, fl, M_, F_, 0, 0, 0, 1);
    ln_f64<1, 1><<<gln, blk, 0, stream>>>(n2, ff, g3, b3, d_out, fl);
}

// Round 5
// 2902.557 us; speedup vs baseline: 1.1216x; 1.1216x over previous
//
#include <hip/hip_runtime.h>
#include <math.h>

// Problem dims (fixed)
#define B_ 2
#define C_ 2048
#define M_ 1024
#define H_ 16
#define KV_ 64
#define F_ 4096

typedef __attribute__((ext_vector_type(8))) __bf16 bf16x8;
typedef __attribute__((ext_vector_type(4))) float f32x4;
typedef unsigned short u16;

#if defined(__has_builtin)
#if __has_builtin(__builtin_amdgcn_mfma_f64_16x16x4f64)
#define HAVE_MFMA64 1
#endif
#endif
#ifndef HAVE_MFMA64
#define HAVE_MFMA64 0
#endif

#if HAVE_MFMA64
typedef __attribute__((ext_vector_type(4))) double f64x4;
#endif

__device__ __forceinline__ float bf2f(u16 u) {
    union { unsigned int i; float f; } x; x.i = ((unsigned int)u) << 16; return x.f;
}
__device__ __forceinline__ u16 f2bf(float f) {
    union { float f; unsigned int i; } x; x.f = f;
    unsigned int r = x.i + 0x7fffu + ((x.i >> 16) & 1u);
    return (u16)(r >> 16);
}
__device__ __forceinline__ float ldflag(const void* p, size_t i, int isf) {
    return isf ? ((const float*)p)[i] : bf2f(((const u16*)p)[i]);
}

__device__ __forceinline__ double blockReduceSumD(double v, double* red, int tid) {
#pragma unroll
    for (int off = 32; off > 0; off >>= 1) v += __shfl_down(v, off, 64);
    if ((tid & 63) == 0) red[tid >> 6] = v;
    __syncthreads();
    v = red[0] + red[1] + red[2] + red[3];
    __syncthreads();
    return v;
}

// ---------------------------------------------------------------------------
// Input-dtype detector (fires fp32 on this harness). flags[0]=1 iff fp32.
// ---------------------------------------------------------------------------
__global__ void detect_dtype(const unsigned int* __restrict__ w, int* __restrict__ flags) {
    __shared__ int cnt[256];
    int t = threadIdx.x, c = 0;
    for (int i = t; i < 2048; i += 256) {
        unsigned int e = (w[i] >> 7) & 0xffu;
        if (e >= 140u || (e > 0u && e < 91u)) c++;
    }
    cnt[t] = c; __syncthreads();
    for (int s = 128; s > 0; s >>= 1) { if (t < s) cnt[t] += cnt[t + s]; __syncthreads(); }
    if (t == 0) flags[0] = (cnt[0] > 300) ? 1 : 0;
}

// ---------------------------------------------------------------------------
// f64 MFMA self-calibration (round-2, HW-validated: cal[0]=1 on gfx950).
// cal[0] = 1 iff the fragment mapping was decoded AND end-to-end verified.
// cal[16 + lane*12 + {0..8}] = {am, ak, bn, bk, colD, rowD0..rowD3}.
// Measured on HW (round 4): the layout is NOT the standard CDNA map
// (cal[1]=0) -- all consumers now use the table only.
// ---------------------------------------------------------------------------
__device__ __forceinline__ float sAval(int m, int k) { return (float)(((m * 5 + k * 3) % 7) - 3); }
__device__ __forceinline__ float sBval(int k, int n) { return (float)(((k * 11 + n * 2) % 5) - 2); }
__device__ __forceinline__ float sQval(int m, int k) { return (float)(((m * 3 + k * 7) % 9) - 4); }
__device__ __forceinline__ float sKval(int c, int k) { return (float)(((c * 5 + k * 2) % 8) - 3); }

__global__ __launch_bounds__(256) void calibrate(int* __restrict__ cal) {
#if HAVE_MFMA64
    __shared__ int ctab[64][12];
    __shared__ int s_ok, s_bad;
    __shared__ float Ast[32][65], Bs[32][65];
    __shared__ float Qv[64][65], Kv[64][65];
    const int t = threadIdx.x;
    if (t == 0) { s_ok = 0; s_bad = 0; }
    __syncthreads();
    if (t < 64) {
        const int l = t;
        f64x4 z = {0.0, 0.0, 0.0, 0.0};
        f64x4 p1 = __builtin_amdgcn_mfma_f64_16x16x4f64(1.0, (double)l, z, 0, 0, 0);
        f64x4 p2 = __builtin_amdgcn_mfma_f64_16x16x4f64((double)l, 1.0, z, 0, 0, 0);
        int ok = 1, bFam = 0, aFam = 0;
        int colD[4], rowD[4];
#pragma unroll
        for (int r = 0; r < 4; r++) {
            double pv = p1[r];
            int f = 0, n = 0;
            if (pv >= 0.0 && pv <= 4096.0) {
                long long vi = (long long)(pv + 0.5);
                if (vi >= 96 && vi <= 156 && ((vi - 96) & 3) == 0) { f = 1; n = (int)((vi - 96) >> 2); }
                else if (vi >= 6 && vi <= 246 && ((vi - 6) & 15) == 0) { f = 2; n = (int)((vi - 6) >> 4); }
            }
            if (f == 0) ok = 0;
            if (r == 0) bFam = f; else if (f != bFam) ok = 0;
            colD[r] = n;
            pv = p2[r]; f = 0; n = 0;
            if (pv >= 0.0 && pv <= 4096.0) {
                long long wi = (long long)(pv + 0.5);
                if (wi >= 96 && wi <= 156 && ((wi - 96) & 3) == 0) { f = 1; n = (int)((wi - 96) >> 2); }
                else if (wi >= 6 && wi <= 246 && ((wi - 6) & 15) == 0) { f = 2; n = (int)((wi - 6) >> 4); }
            }
            if (f == 0) ok = 0;
            if (r == 0) aFam = f; else if (f != aFam) ok = 0;
            rowD[r] = n;
        }
        if (colD[1] != colD[0] || colD[2] != colD[0] || colD[3] != colD[0]) ok = 0;
        int rm = (1 << rowD[0]) | (1 << rowD[1]) | (1 << rowD[2]) | (1 << rowD[3]);
        if (__popc(rm) != 4) ok = 0;
        int cm = 1 << colD[0];
#pragma unroll
        for (int off = 1; off < 16; off <<= 1) {
#pragma unroll
            for (int r = 0; r < 4; r++)
                if (__shfl_xor(rowD[r], off, 64) != rowD[r]) ok = 0;
            cm |= __shfl_xor(cm, off, 64);
        }
        if (cm != 0xffff) ok = 0;
        const int am = (aFam == 2) ? (l >> 2) : (l & 15);
        const int ak = (aFam == 2) ? (l & 3) : (l >> 4);
        const int bn = (bFam == 2) ? (l >> 2) : (l & 15);
        const int bk = (bFam == 2) ? (l & 3) : (l >> 4);
        // probe 3: exact end-to-end check of the decoded mapping
        {
            double a3 = (double)sAval(am, ak);
            double b3 = (double)sBval(bk, bn);
            f64x4 p3 = __builtin_amdgcn_mfma_f64_16x16x4f64(a3, b3, z, 0, 0, 0);
#pragma unroll
            for (int r = 0; r < 4; r++) {
                double ref = 0.0;
                for (int k2 = 0; k2 < 4; k2++)
                    ref += (double)sAval(rowD[r], k2) * (double)sBval(k2, colD[0]);
                if (p3[r] != ref) ok = 0;
            }
        }
        unsigned long long bb = __ballot(ok != 0);
        ctab[l][0] = am; ctab[l][1] = ak; ctab[l][2] = bn; ctab[l][3] = bk;
        ctab[l][4] = colD[0];
        ctab[l][5] = rowD[0]; ctab[l][6] = rowD[1]; ctab[l][7] = rowD[2]; ctab[l][8] = rowD[3];
        ctab[l][9] = 0; ctab[l][10] = 0; ctab[l][11] = 0;
        if (l == 0) s_ok = (bb == ~0ull) ? 1 : 0;
    }
    __syncthreads();
    // synthetic tiles for the structural verification
    for (int i = t; i < 32 * 64; i += 256) {
        int k2 = i >> 6, m2 = i & 63;
        Ast[k2][m2] = sAval(m2, k2);
        Bs[k2][m2] = sBval(k2, m2);
    }
    for (int i = t; i < 64 * 64; i += 256) {
        int r2 = i >> 6, c2 = i & 63;
        Qv[r2][c2] = sQval(r2, c2);
        Kv[r2][c2] = sKval(r2, c2);
    }
    __syncthreads();
    if (s_ok) {
        const int w = t >> 6;
        const int* cl = ctab[t & 63];
        const int am = cl[0], ak2 = cl[1], bn2 = cl[2], bk2 = cl[3], cD = cl[4];
        const int rd[4] = {cl[5], cl[6], cl[7], cl[8]};
        int ok = 1;
        // proj-pattern: D = A(64x32) * B(32x64)
        {
            f64x4 acc4[4] = { {0,0,0,0},{0,0,0,0},{0,0,0,0},{0,0,0,0} };
#pragma unroll
            for (int ks = 0; ks < 8; ks++) {
                double ad = (double)Ast[4 * ks + ak2][16 * w + am];
#pragma unroll
                for (int nt = 0; nt < 4; nt++) {
                    double bd = (double)Bs[4 * ks + bk2][16 * nt + bn2];
                    acc4[nt] = __builtin_amdgcn_mfma_f64_16x16x4f64(ad, bd, acc4[nt], 0, 0, 0);
                }
            }
#pragma unroll
            for (int nt = 0; nt < 4; nt++)
#pragma unroll
                for (int i = 0; i < 4; i++) {
                    int row = 16 * w + rd[i], col = 16 * nt + cD;
                    double ref = 0.0;
                    for (int k2 = 0; k2 < 32; k2++)
                        ref += (double)sAval(row, k2) * (double)sBval(k2, col);
                    if (acc4[nt][i] != ref) ok = 0;
                }
        }
        // attn-pattern: S = Q(16-strip) K^T with K staged [c][k]
        {
            double aqv[16];
#pragma unroll
            for (int ks = 0; ks < 16; ks++)
                aqv[ks] = (double)Qv[16 * w + am][4 * ks + ak2];
            f64x4 S[4] = { {0,0,0,0},{0,0,0,0},{0,0,0,0},{0,0,0,0} };
#pragma unroll
            for (int ks = 0; ks < 16; ks++) {
#pragma unroll
                for (int nt = 0; nt < 4; nt++) {
                    double bd = (double)Kv[16 * nt + bn2][4 * ks + bk2];
                    S[nt] = __builtin_amdgcn_mfma_f64_16x16x4f64(aqv[ks], bd, S[nt], 0, 0, 0);
                }
            }
#pragma unroll
            for (int nt = 0; nt < 4; nt++)
#pragma unroll
                for (int i = 0; i < 4; i++) {
                    int row = 16 * w + rd[i], col = 16 * nt + cD;
                    double ref = 0.0;
                    for (int k2 = 0; k2 < 64; k2++)
                        ref += (double)sQval(row, k2) * (double)sKval(col, k2);
                    if (S[nt][i] != ref) ok = 0;
                }
        }
        if (!ok) s_bad = 1;
    }
    __syncthreads();
    if (t < 64) {
#pragma unroll
        for (int j = 0; j < 12; j++) cal[16 + t * 12 + j] = ctab[t][j];
    }
    if (t == 0) cal[0] = (s_ok && !s_bad) ? 1 : 0;
#else
    if (threadIdx.x == 0) cal[0] = 0;
#endif
}

// ---------------------------------------------------------------------------
// V pre-transpose: vv [bh][c][v] fp32 -> hi/lo bf16 split, layout [bh][v][C].
// ---------------------------------------------------------------------------
__global__ __launch_bounds__(256) void v_to_bf16t(
    const float* __restrict__ vv, u16* __restrict__ hi, u16* __restrict__ lo)
{
    __shared__ float Ls[64][65];
    const int bh = blockIdx.y, c0 = blockIdx.x * 64;
    const int t = threadIdx.x;
    const int c = t >> 2, vb = (t & 3) * 16;
    const float* src = vv + ((size_t)bh * C_ + c0 + c) * KV_ + vb;
#pragma unroll
    for (int i = 0; i < 4; i++) {
        float4 p = *(const float4*)(src + 4 * i);
        Ls[vb + 4*i + 0][c] = p.x;
        Ls[vb + 4*i + 1][c] = p.y;
        Ls[vb + 4*i + 2][c] = p.z;
        Ls[vb + 4*i + 3][c] = p.w;
    }
    __syncthreads();
#pragma unroll
    for (int it = 0; it < 2; it++) {
        int idx = t + 256 * it;            // 0..511 : 64 rows x 8 chunks
        int v = idx >> 3, ch = idx & 7;
        u16 h8[8], l8[8];
#pragma unroll
        for (int j = 0; j < 8; j++) {
            float x = Ls[v][ch * 8 + j];
            h8[j] = f2bf(x);
            l8[j] = f2bf(x - bf2f(h8[j]));
        }
        size_t off = ((size_t)bh * KV_ + v) * C_ + c0 + ch * 8;
        int4 hp, lp;
        hp.x = (int)((unsigned)h8[0] | ((unsigned)h8[1] << 16));
        hp.y = (int)((unsigned)h8[2] | ((unsigned)h8[3] << 16));
        hp.z = (int)((unsigned)h8[4] | ((unsigned)h8[5] << 16));
        hp.w = (int)((unsigned)h8[6] | ((unsigned)h8[7] << 16));
        lp.x = (int)((unsigned)l8[0] | ((unsigned)l8[1] << 16));
        lp.y = (int)((unsigned)l8[2] | ((unsigned)l8[3] << 16));
        lp.z = (int)((unsigned)l8[4] | ((unsigned)l8[5] << 16));
        lp.w = (int)((unsigned)l8[6] | ((unsigned)l8[7] << 16));
        *(int4*)(hi + off) = hp;
        *(int4*)(lo + off) = lp;
    }
}

// ---------------------------------------------------------------------------
// Q/K projection GEMM: fp64 ACCUMULATION, fp32 LDS tiles. (round-2, passing)
// ---------------------------------------------------------------------------
template<int AMODE>
__global__ __launch_bounds__(256) void proj_qk64(
    const void* __restrict__ Ab, const void* __restrict__ Bb,
    float* __restrict__ Cb, const int* __restrict__ flags,
    const int* __restrict__ cal,
    int N, int Kd, long long a_bstr, long long b_hstr, long long c_zstr, int NH)
{
    const int isf = flags[0];
    const int isfA = (AMODE == 1) ? 1 : isf;
    __shared__ float Ast[32][65];   // [k][m]
    __shared__ float Bs[32][65];    // [k][n]
    const int t = threadIdx.x;
    const int m0 = blockIdx.x * 64, n0 = blockIdx.y * 64;
    const int zb = blockIdx.z / NH, zh = blockIdx.z % NH;
    const size_t aoff = (size_t)zb * a_bstr, boff = (size_t)zh * b_hstr;
    const size_t czoff = (size_t)blockIdx.z * c_zstr;
    const int ar = t >> 2, ak = (t & 3) * 8;
    const int bk = t >> 3, bn = (t & 7) * 8;
    const int cok = cal[0];

#if HAVE_MFMA64
    if (cok) {
        const int* cl = cal + 16 + (t & 63) * 12;
        const int am = cl[0], ak2 = cl[1], bn2 = cl[2], bk2 = cl[3], cD = cl[4];
        const int rd[4] = {cl[5], cl[6], cl[7], cl[8]};
        const int w = t >> 6;
        f64x4 acc4[4] = { {0,0,0,0},{0,0,0,0},{0,0,0,0},{0,0,0,0} };
        for (int k0 = 0; k0 < Kd; k0 += 32) {
            float av[8];
            {
                size_t off = aoff + (size_t)(m0 + ar) * Kd + k0 + ak;
                if (isfA) {
                    const float* ap = (const float*)Ab + off;
                    float4 p0 = *(const float4*)ap, p1 = *((const float4*)ap + 1);
                    av[0]=p0.x; av[1]=p0.y; av[2]=p0.z; av[3]=p0.w;
                    av[4]=p1.x; av[5]=p1.y; av[6]=p1.z; av[7]=p1.w;
                } else {
                    const u16* ap = (const u16*)Ab + off;
                    int4 p = *(const int4*)ap;
                    unsigned int u[4] = {(unsigned)p.x,(unsigned)p.y,(unsigned)p.z,(unsigned)p.w};
#pragma unroll
                    for (int j = 0; j < 4; j++) {
                        av[2*j]   = bf2f((u16)(u[j] & 0xffffu));
                        av[2*j+1] = bf2f((u16)(u[j] >> 16));
                    }
                }
            }
#pragma unroll
            for (int j = 0; j < 8; j++) Ast[ak + j][ar] = av[j];
            float bv[8];
            {
                size_t off = boff + (size_t)(k0 + bk) * N + n0 + bn;
                if (isf) {
                    const float* bp = (const float*)Bb + off;
                    float4 p0 = *(const float4*)bp, p1 = *((const float4*)bp + 1);
                    bv[0]=p0.x; bv[1]=p0.y; bv[2]=p0.z; bv[3]=p0.w;
                    bv[4]=p1.x; bv[5]=p1.y; bv[6]=p1.z; bv[7]=p1.w;
                } else {
                    const u16* bp = (const u16*)Bb + off;
                    int4 p = *(const int4*)bp;
                    unsigned int u[4] = {(unsigned)p.x,(unsigned)p.y,(unsigned)p.z,(unsigned)p.w};
#pragma unroll
                    for (int j = 0; j < 4; j++) {
                        bv[2*j]   = bf2f((u16)(u[j] & 0xffffu));
                        bv[2*j+1] = bf2f((u16)(u[j] >> 16));
                    }
                }
            }
#pragma unroll
            for (int j = 0; j < 8; j++) Bs[bk][bn + j] = bv[j];
            __syncthreads();
#pragma unroll
            for (int ks = 0; ks < 8; ks++) {
                double ad = (double)Ast[4 * ks + ak2][16 * w + am];
#pragma unroll
                for (int nt = 0; nt < 4; nt++) {
                    double bd = (double)Bs[4 * ks + bk2][16 * nt + bn2];
                    acc4[nt] = __builtin_amdgcn_mfma_f64_16x16x4f64(ad, bd, acc4[nt], 0, 0, 0);
                }
            }
            __syncthreads();
        }
#pragma unroll
        for (int nt = 0; nt < 4; nt++)
#pragma unroll
            for (int i = 0; i < 4; i++)
                Cb[czoff + (size_t)(m0 + 16 * w + rd[i]) * N + n0 + 16 * nt + cD] =
                    (float)acc4[nt][i];
        return;
    }
#endif
    // ---- legacy scalar-fp64 path (round-0, passing) ----
    double acc[4][4] = {};
    for (int k0 = 0; k0 < Kd; k0 += 32) {
        float av[8];
        {
            size_t off = aoff + (size_t)(m0 + ar) * Kd + k0 + ak;
            if (isfA) {
                const float* ap = (const float*)Ab + off;
                float4 p0 = *(const float4*)ap, p1 = *((const float4*)ap + 1);
                av[0]=p0.x; av[1]=p0.y; av[2]=p0.z; av[3]=p0.w;
                av[4]=p1.x; av[5]=p1.y; av[6]=p1.z; av[7]=p1.w;
            } else {
                const u16* ap = (const u16*)Ab + off;
                int4 p = *(const int4*)ap;
                unsigned int u[4] = {(unsigned)p.x,(unsigned)p.y,(unsigned)p.z,(unsigned)p.w};
#pragma unroll
                for (int j = 0; j < 4; j++) {
                    av[2*j]   = bf2f((u16)(u[j] & 0xffffu));
                    av[2*j+1] = bf2f((u16)(u[j] >> 16));
                }
            }
        }
#pragma unroll
        for (int j = 0; j < 8; j++) Ast[ak + j][ar] = av[j];
        float bv[8];
        {
            size_t off = boff + (size_t)(k0 + bk) * N + n0 + bn;
            if (isf) {
                const float* bp = (const float*)Bb + off;
                float4 p0 = *(const float4*)bp, p1 = *((const float4*)bp + 1);
                bv[0]=p0.x; bv[1]=p0.y; bv[2]=p0.z; bv[3]=p0.w;
                bv[4]=p1.x; bv[5]=p1.y; bv[6]=p1.z; bv[7]=p1.w;
            } else {
                const u16* bp = (const u16*)Bb + off;
                int4 p = *(const int4*)bp;
                unsigned int u[4] = {(unsigned)p.x,(unsigned)p.y,(unsigned)p.z,(unsigned)p.w};
#pragma unroll
                for (int j = 0; j < 4; j++) {
                    bv[2*j]   = bf2f((u16)(u[j] & 0xffffu));
                    bv[2*j+1] = bf2f((u16)(u[j] >> 16));
                }
            }
        }
#pragma unroll
        for (int j = 0; j < 8; j++) Bs[bk][bn + j] = bv[j];
        __syncthreads();
        const int r0 = (t & 15) * 4, c0 = (t >> 4) * 4;
#pragma unroll
        for (int kk = 0; kk < 32; kk++) {
            float4 a4 = *(const float4*)&Ast[kk][r0];
            float4 b4 = *(const float4*)&Bs[kk][c0];
            double a0=a4.x, a1=a4.y, a2=a4.z, a3=a4.w;
            double b0=b4.x, b1=b4.y, b2=b4.z, b3=b4.w;
            acc[0][0] += a0*b0; acc[0][1] += a0*b1; acc[0][2] += a0*b2; acc[0][3] += a0*b3;
            acc[1][0] += a1*b0; acc[1][1] += a1*b1; acc[1][2] += a1*b2; acc[1][3] += a1*b3;
            acc[2][0] += a2*b0; acc[2][1] += a2*b1; acc[2][2] += a2*b2; acc[2][3] += a2*b3;
            acc[3][0] += a3*b0; acc[3][1] += a3*b1; acc[3][2] += a3*b2; acc[3][3] += a3*b3;
        }
        __syncthreads();
    }
    {
        const int r0 = (t & 15) * 4, c0 = (t >> 4) * 4;
#pragma unroll
        for (int i = 0; i < 4; i++)
#pragma unroll
            for (int j = 0; j < 4; j++)
                Cb[czoff + (size_t)(m0 + r0 + i) * N + n0 + c0 + j] = (float)acc[i][j];
    }
}

// ---------------------------------------------------------------------------
// MFMA GEMM with bf16 hi/lo 3-term split (post-softmax ops). Unchanged.
// ---------------------------------------------------------------------------
template<int AMODE, bool RELU, bool BIAS>
__global__ __launch_bounds__(256) void gemm_hilo(
    const void* __restrict__ Ab, const void* __restrict__ Bb,
    float* __restrict__ Cb, const void* __restrict__ bias,
    const int* __restrict__ flags,
    int N, int Kd, long long a_bstr, long long b_hstr, long long c_zstr, int NH)
{
    const int isf = flags[0];
    const int aIsF32 = (AMODE == 1) ? 1 : isf;
    __shared__ u16 a_hi[64][40], a_lo[64][40];
    __shared__ u16 b_hi[64][40], b_lo[64][40];

    const int tid = threadIdx.x;
    const int w = tid >> 6, l = tid & 63;
    const int lq = l & 15, quad = l >> 4;
    const int m0 = blockIdx.x * 64, n0 = blockIdx.y * 64;
    const int zb = blockIdx.z / NH, zh = blockIdx.z % NH;
    const size_t aoff = (size_t)zb * a_bstr, boff = (size_t)zh * b_hstr;

    f32x4 acc[4] = { {0,0,0,0},{0,0,0,0},{0,0,0,0},{0,0,0,0} };
    const int arow = tid >> 2, ac8 = (tid & 3) * 8;
    const int bk = tid >> 3, bn8 = (tid & 7) * 8;

    for (int k0 = 0; k0 < Kd; k0 += 32) {
        {
            size_t off = aoff + (size_t)(m0 + arow) * Kd + k0 + ac8;
            u16 hh[8], ll[8];
            if (aIsF32) {
                const float* ap = (const float*)Ab + off;
                float4 p0 = *(const float4*)ap, p1 = *((const float4*)ap + 1);
                float vv[8] = {p0.x,p0.y,p0.z,p0.w,p1.x,p1.y,p1.z,p1.w};
#pragma unroll
                for (int j = 0; j < 8; j++) {
                    hh[j] = f2bf(vv[j]);
                    ll[j] = f2bf(vv[j] - bf2f(hh[j]));
                }
            } else {
                int4 p = *(const int4*)((const u16*)Ab + off);
                unsigned int u[4] = {(unsigned)p.x,(unsigned)p.y,(unsigned)p.z,(unsigned)p.w};
#pragma unroll
                for (int j = 0; j < 4; j++) {
                    hh[2*j]   = (u16)(u[j] & 0xffffu);
                    hh[2*j+1] = (u16)(u[j] >> 16);
                    ll[2*j] = 0; ll[2*j+1] = 0;
                }
            }
            int4 ph, pl;
            ph.x = (int)((unsigned)hh[0] | ((unsigned)hh[1] << 16));
            ph.y = (int)((unsigned)hh[2] | ((unsigned)hh[3] << 16));
            ph.z = (int)((unsigned)hh[4] | ((unsigned)hh[5] << 16));
            ph.w = (int)((unsigned)hh[6] | ((unsigned)hh[7] << 16));
            pl.x = (int)((unsigned)ll[0] | ((unsigned)ll[1] << 16));
            pl.y = (int)((unsigned)ll[2] | ((unsigned)ll[3] << 16));
            pl.z = (int)((unsigned)ll[4] | ((unsigned)ll[5] << 16));
            pl.w = (int)((unsigned)ll[6] | ((unsigned)ll[7] << 16));
            *(int4*)&a_hi[arow][ac8] = ph;
            *(int4*)&a_lo[arow][ac8] = pl;
        }
        {
            size_t off = boff + (size_t)(k0 + bk) * N + n0 + bn8;
            u16 hh[8], ll[8];
            if (isf) {
                const float* bp = (const float*)Bb + off;
                float4 p0 = *(const float4*)bp, p1 = *((const float4*)bp + 1);
                float vv[8] = {p0.x,p0.y,p0.z,p0.w,p1.x,p1.y,p1.z,p1.w};
#pragma unroll
                for (int j = 0; j < 8; j++) {
                    hh[j] = f2bf(vv[j]);
                    ll[j] = f2bf(vv[j] - bf2f(hh[j]));
                }
            } else {
                int4 p = *(const int4*)((const u16*)Bb + off);
                unsigned int u[4] = {(unsigned)p.x,(unsigned)p.y,(unsigned)p.z,(unsigned)p.w};
#pragma unroll
                for (int j = 0; j < 4; j++) {
                    hh[2*j]   = (u16)(u[j] & 0xffffu);
                    hh[2*j+1] = (u16)(u[j] >> 16);
                    ll[2*j] = 0; ll[2*j+1] = 0;
                }
            }
#pragma unroll
            for (int j = 0; j < 8; j++) {
                b_hi[bn8 + j][bk] = hh[j];
                b_lo[bn8 + j][bk] = ll[j];
            }
        }
        __syncthreads();
        bf16x8 ah = *(bf16x8*)&a_hi[w * 16 + lq][quad * 8];
        bf16x8 al = *(bf16x8*)&a_lo[w * 16 + lq][quad * 8];
#pragma unroll
        for (int nt = 0; nt < 4; nt++) {
            bf16x8 bh = *(bf16x8*)&b_hi[nt * 16 + lq][quad * 8];
            bf16x8 bl = *(bf16x8*)&b_lo[nt * 16 + lq][quad * 8];
            acc[nt] = __builtin_amdgcn_mfma_f32_16x16x32_bf16(ah, bh, acc[nt], 0, 0, 0);
            acc[nt] = __builtin_amdgcn_mfma_f32_16x16x32_bf16(ah, bl, acc[nt], 0, 0, 0);
            acc[nt] = __builtin_amdgcn_mfma_f32_16x16x32_bf16(al, bh, acc[nt], 0, 0, 0);
        }
        __syncthreads();
    }

    const int rowb = m0 + w * 16 + quad * 4;
    const size_t czoff = (size_t)blockIdx.z * c_zstr;
#pragma unroll
    for (int nt = 0; nt < 4; nt++) {
        int col = n0 + nt * 16 + lq;
        float bv = BIAS ? ldflag(bias, col, isf) : 0.0f;
#pragma unroll
        for (int r = 0; r < 4; r++) {
            float val = acc[nt][r] + bv;
            if (RELU) val = fmaxf(val, 0.0f);
            Cb[czoff + (size_t)(rowb + r) * N + col] = val;
        }
    }
}

// ---------------------------------------------------------------------------
// FAST attention: f64 QK^T (calibrated table mapping -- NO layout assumption)
// + PV on the bf16 matrix pipe (hi/lo 3-term).
// Bridge between the (non-standard) f64 D-layout and the verified bf16
// fragment maps: P is written to a wave-private LDS slab at its ABSOLUTE
// within-strip row rd[i]; the bf16 A-fragment reads the slab through its own
// row=l&15 map, so any calibrated f64 layout works. The per-row softmax
// state (alpha, l) is re-indexed from f64-rows to bf16-rows via 64-entry
// LDS tables (one writer lane per 16-lane group; wave-internal lgkmcnt
// fence per guide rule #18).
// LDS = 52736 B -> 3 blocks/CU (round-2/4 attn had 61952 -> 2 blocks/CU).
// Runs iff cal[0]==1 (HW-proven in rounds 2+4); else exits (legacy runs).
// Mask quirk faithful: -100 on UNSCALED fp64 logit when key <= query.
// ---------------------------------------------------------------------------
__global__ __launch_bounds__(256) void attn_fast(
    const float* __restrict__ q, const float* __restrict__ k,
    const u16* __restrict__ vthi, const u16* __restrict__ vtlo,
    float* __restrict__ pre,
    const int* __restrict__ cal, int masked)
{
#if HAVE_MFMA64
    __shared__ float Ks[64][68];          // Q staging, then K tile [c][k]
    __shared__ u16 VtH[64][68];           // V^T hi tile [v][c]
    __shared__ u16 VtL[64][68];           // V^T lo tile [v][c]
    __shared__ u16 Pslab[4][2][16][68];   // [wave][hi/lo][q-row][c]
    __shared__ float alphaT[64];          // per-row alpha (this tile)
    __shared__ float lT[64];              // per-row l (epilogue)

    if (cal[0] == 0) return;

    const int idx = blockIdx.x;
    const int q0 = (idx & (C_ / 64 - 1)) * 64;
    const int h = (idx >> 5) & (H_ - 1);
    const int b = idx >> 9;
    const size_t bh = (size_t)(b * H_ + h);
    const float* Qg = q + (bh * C_ + q0) * KV_;
    const float* Kg = k + bh * C_ * KV_;
    const u16* vthg = vthi + bh * (size_t)KV_ * C_;
    const u16* vtlg = vtlo + bh * (size_t)KV_ * C_;

    const int t = threadIdx.x;
    const int* cl = cal + 16 + (t & 63) * 12;
    const int am = cl[0], ak2 = cl[1], bn2 = cl[2], bk2 = cl[3], cD = cl[4];
    const int rdv[4] = {cl[5], cl[6], cl[7], cl[8]};
    const int w = t >> 6, l15 = t & 15, g = (t >> 4) & 3;
    const int srow = t >> 2, sc = (t & 3) * 16;

    {   // stage Q [q][k]
        const float* src = Qg + (size_t)srow * KV_ + sc;
#pragma unroll
        for (int i = 0; i < 4; i++)
            *(float4*)&Ks[srow][sc + 4 * i] = *(const float4*)(src + 4 * i);
    }
    __syncthreads();
    double aq[16];
#pragma unroll
    for (int ks = 0; ks < 16; ks++)
        aq[ks] = (double)Ks[16 * w + am][4 * ks + ak2];

    f32x4 acc[4] = { {0,0,0,0},{0,0,0,0},{0,0,0,0},{0,0,0,0} };
    float mreg[4] = {-3.0e38f, -3.0e38f, -3.0e38f, -3.0e38f};
    float lreg[4] = {0.0f, 0.0f, 0.0f, 0.0f};

    for (int kt = 0; kt < 32; kt++) {
        const int c0 = kt * 64;
        __syncthreads();   // prev tile (and aq reads at kt=0) fully consumed
        {   // stage K fp32 [c][k]
            const float* ksrc = Kg + (size_t)(c0 + srow) * KV_ + sc;
#pragma unroll
            for (int i = 0; i < 4; i++)
                *(float4*)&Ks[srow][sc + 4 * i] = *(const float4*)(ksrc + 4 * i);
        }
        // stage Vt hi/lo tiles (B-frag-ready rows, contiguous in keys)
#pragma unroll
        for (int it = 0; it < 4; it++) {
            int idx2 = t + 256 * it;
            int arr = idx2 >> 9, rem = idx2 & 511;
            int vrow = rem >> 3, ch = rem & 7;
            const u16* gsrc = (arr ? vtlg : vthg) + (size_t)vrow * C_ + c0 + ch * 8;
            u16* dst = (arr ? &VtL[vrow][ch * 8] : &VtH[vrow][ch * 8]);
            int4 d = *(const int4*)gsrc;
            *(int2*)dst = make_int2(d.x, d.y);
            *(int2*)(dst + 4) = make_int2(d.z, d.w);
        }
        __syncthreads();

        // S strip (16 q x 64 keys) in fp64 on the matrix pipe
        f64x4 S[4] = { {0,0,0,0},{0,0,0,0},{0,0,0,0},{0,0,0,0} };
#pragma unroll
        for (int ks = 0; ks < 16; ks++) {
#pragma unroll
            for (int nt = 0; nt < 4; nt++) {
                double bd = (double)Ks[16 * nt + bn2][4 * ks + bk2];
                S[nt] = __builtin_amdgcn_mfma_f64_16x16x4f64(aq[ks], bd, S[nt], 0, 0, 0);
            }
        }
        if (masked) {
#pragma unroll
            for (int nt = 0; nt < 4; nt++) {
                const int cg = c0 + 16 * nt + cD;
#pragma unroll
                for (int i = 0; i < 4; i++)
                    if (cg <= q0 + 16 * w + rdv[i]) S[nt][i] -= 100.0;
            }
        }
        // wave-local online softmax on f64-rows rdv[i] (uniform per group)
        float tm[4];
#pragma unroll
        for (int i = 0; i < 4; i++)
            tm[i] = fmaxf(fmaxf((float)S[0][i], (float)S[1][i]),
                          fmaxf((float)S[2][i], (float)S[3][i]));
#pragma unroll
        for (int off = 1; off < 16; off <<= 1)
#pragma unroll
            for (int i = 0; i < 4; i++)
                tm[i] = fmaxf(tm[i], __shfl_xor(tm[i], off, 64));
        float alpha[4];
#pragma unroll
        for (int i = 0; i < 4; i++) {
            const float mo = mreg[i];
            const float mn = fmaxf(mo, tm[i]);
            alpha[i] = (mo < -1.0e37f) ? 0.0f : __expf(0.125f * (mo - mn));
            mreg[i] = mn;
        }
        if (l15 == 0) {
#pragma unroll
            for (int i = 0; i < 4; i++) alphaT[16 * w + rdv[i]] = alpha[i];
        }
        // P = exp(0.125(S-m)) -> bf16 hi/lo slab at row rdv[i], col 16nt+cD
        float ts[4] = {0.0f, 0.0f, 0.0f, 0.0f};
#pragma unroll
        for (int nt = 0; nt < 4; nt++) {
#pragma unroll
            for (int i = 0; i < 4; i++) {
                float p = __expf((float)(0.125 * (S[nt][i] - (double)mreg[i])));
                ts[i] += p;
                u16 ph = f2bf(p);
                u16 pl = f2bf(p - bf2f(ph));
                Pslab[w][0][rdv[i]][16 * nt + cD] = ph;
                Pslab[w][1][rdv[i]][16 * nt + cD] = pl;
            }
        }
#pragma unroll
        for (int off = 1; off < 16; off <<= 1)
#pragma unroll
            for (int i = 0; i < 4; i++)
                ts[i] += __shfl_xor(ts[i], off, 64);
#pragma unroll
        for (int i = 0; i < 4; i++)
            lreg[i] = lreg[i] * alpha[i] + ts[i];

        // wave-internal LDS write->read fence (cross-lane, same wave)
        __builtin_amdgcn_sched_barrier(0);
        asm volatile("s_waitcnt lgkmcnt(0)" ::: "memory");
        __builtin_amdgcn_sched_barrier(0);

        // re-index alpha to bf16-D rows 4g+i, rescale accumulators
        float af[4];
#pragma unroll
        for (int i = 0; i < 4; i++) af[i] = alphaT[16 * w + 4 * g + i];
#pragma unroll
        for (int nt = 0; nt < 4; nt++)
#pragma unroll
            for (int i = 0; i < 4; i++) acc[nt][i] *= af[i];

        // PV on the bf16 matrix pipe: 3-term hi/lo, 2 x K=32 steps
        union F8 { struct { int2 a, b; } p; bf16x8 v; };
#pragma unroll
        for (int ks2 = 0; ks2 < 2; ks2++) {
            const u16* pa = &Pslab[w][0][l15][8 * g + 32 * ks2];
            const u16* pb = &Pslab[w][1][l15][8 * g + 32 * ks2];
            F8 pah, pal;
            pah.p.a = *(const int2*)pa; pah.p.b = *(const int2*)(pa + 4);
            pal.p.a = *(const int2*)pb; pal.p.b = *(const int2*)(pb + 4);
#pragma unroll
            for (int nt = 0; nt < 4; nt++) {
                const u16* vh = &VtH[16 * nt + l15][8 * g + 32 * ks2];
                const u16* vl = &VtL[16 * nt + l15][8 * g + 32 * ks2];
                F8 vbh, vbl;
                vbh.p.a = *(const int2*)vh; vbh.p.b = *(const int2*)(vh + 4);
                vbl.p.a = *(const int2*)vl; vbl.p.b = *(const int2*)(vl + 4);
                acc[nt] = __builtin_amdgcn_mfma_f32_16x16x32_bf16(pah.v, vbh.v, acc[nt], 0, 0, 0);
                acc[nt] = __builtin_amdgcn_mfma_f32_16x16x32_bf16(pah.v, vbl.v, acc[nt], 0, 0, 0);
                acc[nt] = __builtin_amdgcn_mfma_f32_16x16x32_bf16(pal.v, vbh.v, acc[nt], 0, 0, 0);
            }
        }
    }
    // epilogue: re-index l to bf16-D rows; out = O / l; pre [B, C, H, V]
    if (l15 == 0) {
#pragma unroll
        for (int i = 0; i < 4; i++) lT[16 * w + rdv[i]] = lreg[i];
    }
    __builtin_amdgcn_sched_barrier(0);
    asm volatile("s_waitcnt lgkmcnt(0)" ::: "memory");
    __builtin_amdgcn_sched_barrier(0);
#pragma unroll
    for (int i = 0; i < 4; i++) {
        const float li = lT[16 * w + 4 * g + i];
        const size_t rbase = (((size_t)b * C_ + q0 + 16 * w + 4 * g + i) * H_ + h) * KV_;
#pragma unroll
        for (int nt = 0; nt < 4; nt++)
            pre[rbase + 16 * nt + l15] = acc[nt][i] / li;
    }
#endif
}

// ---------------------------------------------------------------------------
// LEGACY attention (round-0, passing, scalar fp64). Runs iff cal[0]==0.
// ---------------------------------------------------------------------------
__global__ __launch_bounds__(256) void attn_legacy(
    const float* __restrict__ q, const float* __restrict__ k,
    const float* __restrict__ v, float* __restrict__ pre,
    const int* __restrict__ cal, int masked)
{
    __shared__ float Qs[64][68];
    __shared__ float KPs[64][68];
    __shared__ float Vs[64][68];
    __shared__ float redm[64][17];
    __shared__ float redl[64][17];
    __shared__ float mrow[64], lrow[64], arow[64];

    if (cal[0] != 0) return;

    const int idx = blockIdx.x;
    const int q0 = (idx & (C_ / 64 - 1)) * 64;
    const int h = (idx >> 5) & (H_ - 1);
    const int b = idx >> 9;
    const size_t bh = (size_t)(b * H_ + h);
    const float* Qg = q + (bh * C_ + q0) * KV_;
    const float* Kg = k + bh * C_ * KV_;
    const float* Vg = v + bh * C_ * KV_;
    const int t = threadIdx.x;
    const int tq = t & 15, tc = t >> 4;
    const int srow = t >> 2, scol = (t & 3) * 16;

    {
        const float* src = Qg + (size_t)srow * KV_ + scol;
#pragma unroll
        for (int i = 0; i < 4; i++) {
            float4 p4 = *(const float4*)(src + 4 * i);
            Qs[scol + 4*i + 0][srow] = p4.x;
            Qs[scol + 4*i + 1][srow] = p4.y;
            Qs[scol + 4*i + 2][srow] = p4.z;
            Qs[scol + 4*i + 3][srow] = p4.w;
        }
    }
    if (t < 64) { mrow[t] = -3.0e38f; lrow[t] = 0.0f; }

    float O[4][4] = {};

    for (int kt = 0; kt < 32; kt++) {
        const int c0 = kt * 64;
        __syncthreads();
        {
            const float* ksrc = Kg + (size_t)(c0 + srow) * KV_ + scol;
#pragma unroll
            for (int i = 0; i < 4; i++) {
                float4 p4 = *(const float4*)(ksrc + 4 * i);
                KPs[scol + 4*i + 0][srow] = p4.x;
                KPs[scol + 4*i + 1][srow] = p4.y;
                KPs[scol + 4*i + 2][srow] = p4.z;
                KPs[scol + 4*i + 3][srow] = p4.w;
            }
            const float* vsrc = Vg + (size_t)(c0 + srow) * KV_ + scol;
#pragma unroll
            for (int i = 0; i < 4; i++)
                *(float4*)&Vs[srow][scol + 4 * i] = *(const float4*)(vsrc + 4 * i);
        }
        __syncthreads();

        double Sd[4][4] = {};
#pragma unroll 4
        for (int j = 0; j < 64; j++) {
            float4 qa = *(const float4*)&Qs[j][4 * tq];
            float4 kb = *(const float4*)&KPs[j][4 * tc];
            double qd[4] = {qa.x, qa.y, qa.z, qa.w};
            double kd[4] = {kb.x, kb.y, kb.z, kb.w};
#pragma unroll
            for (int i = 0; i < 4; i++)
#pragma unroll
                for (int jj = 0; jj < 4; jj++)
                    Sd[i][jj] += qd[i] * kd[jj];
        }
        if (masked) {
#pragma unroll
            for (int i = 0; i < 4; i++)
#pragma unroll
                for (int jj = 0; jj < 4; jj++)
                    if (c0 + 4 * tc + jj <= q0 + 4 * tq + i) Sd[i][jj] -= 100.0;
        }
#pragma unroll
        for (int i = 0; i < 4; i++) {
            double mm = fmax(fmax(Sd[i][0], Sd[i][1]), fmax(Sd[i][2], Sd[i][3]));
            redm[4 * tq + i][tc] = (float)mm;
        }
        __syncthreads();
        if (t < 64) {
            float tmv = redm[t][0];
#pragma unroll
            for (int x = 1; x < 16; x++) tmv = fmaxf(tmv, redm[t][x]);
            float mo = mrow[t];
            float mn = fmaxf(mo, tmv);
            arow[t] = (mo < -1.0e37f) ? 0.0f
                       : (float)exp(0.125 * ((double)mo - (double)mn));
            mrow[t] = mn;
        }
        __syncthreads();
#pragma unroll
        for (int i = 0; i < 4; i++) {
            double mn = (double)mrow[4 * tq + i];
            float ls = 0.0f;
#pragma unroll
            for (int jj = 0; jj < 4; jj++) {
                float p = (float)exp(0.125 * (Sd[i][jj] - mn));
                KPs[4 * tc + jj][4 * tq + i] = p;
                ls += p;
            }
            redl[4 * tq + i][tc] = ls;
        }
        __syncthreads();
        if (t < 64) {
            float s = 0.0f;
#pragma unroll
            for (int x = 0; x < 16; x++) s += redl[t][x];
            lrow[t] = lrow[t] * arow[t] + s;
        }
        float al[4];
#pragma unroll
        for (int i = 0; i < 4; i++) al[i] = arow[4 * tq + i];
#pragma unroll
        for (int i = 0; i < 4; i++)
#pragma unroll
            for (int jj = 0; jj < 4; jj++) O[i][jj] *= al[i];
#pragma unroll 4
        for (int c = 0; c < 64; c++) {
            float4 pa = *(const float4*)&KPs[c][4 * tq];
            float4 vb = *(const float4*)&Vs[c][4 * tc];
            float pd[4] = {pa.x, pa.y, pa.z, pa.w};
            float vd[4] = {vb.x, vb.y, vb.z, vb.w};
#pragma unroll
            for (int i = 0; i < 4; i++)
#pragma unroll
                for (int jj = 0; jj < 4; jj++)
                    O[i][jj] += pd[i] * vd[jj];
        }
    }
    __syncthreads();
#pragma unroll
    for (int i = 0; i < 4; i++) {
        float li = lrow[4 * tq + i];
        float4 o4;
        o4.x = O[i][0] / li; o4.y = O[i][1] / li;
        o4.z = O[i][2] / li; o4.w = O[i][3] / li;
        *(float4*)&pre[(((size_t)b * C_ + q0 + 4 * tq + i) * H_ + h) * KV_ + 4 * tc] = o4;
    }
}

// ---------------------------------------------------------------------------
// Residual + LayerNorm, fp64 stats, fp32 storage. In-place safe. Unchanged.
// ---------------------------------------------------------------------------
template<int IN1MODE, int OUTMODE>
__global__ __launch_bounds__(256) void ln_f64(
    const void* __restrict__ in1, const float* __restrict__ in2,
    const void* __restrict__ g, const void* __restrict__ b,
    void* __restrict__ out, const int* __restrict__ flags)
{
    __shared__ double buf[M_];
    __shared__ double red[4];
    const int isf = flags[0];
    const int row = blockIdx.x;
    const size_t base = (size_t)row * M_;
    const int tid = threadIdx.x;
    double s = 0.0;
    for (int i = tid; i < M_; i += 256) {
        double v1 = (IN1MODE == 1) ? (double)((const float*)in1)[base + i]
                                   : (double)ldflag(in1, base + i, isf);
        double val = v1 + (double)in2[base + i];
        buf[i] = val;
        s += val;
    }
    s = blockReduceSumD(s, red, tid);
    const double mu = s * (1.0 / M_);
    double vs = 0.0;
    for (int i = tid; i < M_; i += 256) { double dd = buf[i] - mu; vs += dd * dd; }
    vs = blockReduceSumD(vs, red, tid);
    const double rstd = 1.0 / sqrt(vs * (1.0 / M_) + 1e-5);
    for (int i = tid; i < M_; i += 256) {
        double y = (buf[i] - mu) * rstd * (double)ldflag(g, i, isf) + (double)ldflag(b, i, isf);
        if (OUTMODE == 0) ((float*)out)[base + i] = (float)y;
        else if (isf)     ((float*)out)[base + i] = (float)y;
        else              ((u16*)out)[base + i] = f2bf((float)y);
    }
}

// ---------------------------------------------------------------------------
extern "C" void kernel_launch(void* const* d_in, const int* in_sizes, int n_in,
                              void* d_out, int out_size, void* d_ws, size_t ws_size,
                              hipStream_t stream)
{
    const void* enc = d_in[0];
    const void* x   = d_in[1];
    const void* wq1 = d_in[2];
    const void* wk1 = d_in[3];
    const void* wv1 = d_in[4];
    const void* wo1 = d_in[5];
    const void* g1  = d_in[6];
    const void* b1  = d_in[7];
    const void* wq2 = d_in[8];
    const void* wk2 = d_in[9];
    const void* wv2 = d_in[10];
    const void* wo2 = d_in[11];
    const void* g2  = d_in[12];
    const void* b2  = d_in[13];
    const void* fw1 = d_in[14];
    const void* fb1 = d_in[15];
    const void* fw2 = d_in[16];
    const void* fb2 = d_in[17];
    const void* g3  = d_in[18];
    const void* b3  = d_in[19];

    int* fl = (int*)d_ws;
    int* cal = fl + 16;                                // [0]=ok, [16..] lane table
    const size_t NQ = (size_t)B_ * C_ * M_;            // 4,194,304
    // Aliasing as the PASSING rounds:
    // S0: q1/q2 -> h1[0] | S1: k1->attout1->k2->attout2 -> h1[1]
    // S2: v1->v2 -> h1[2] | S3: pre1->pre2 -> h1[3] | S4: n1 -> n2 (in-place)
    // Vt scratch: attn1 -> S4 (dead until ln1), attn2 -> d_out (dead until FFN).
    float* S0 = (float*)((char*)d_ws + 4096);
    float* S1 = S0 + NQ;
    float* S2 = S1 + NQ;
    float* S3 = S2 + NQ;
    float* S4 = S3 + NQ;
    float* q = S0, *kk = S1, *vv = S2, *pre = S3, *attout = S1, *n1 = S4, *n2 = S4;
    float* h1 = S0;                                    // fp32 [4096,4096] = S0..S3
    float* ff = (float*)d_out;
    u16* vt1h = (u16*)S4;                              // 2*16*64*2048 u16 = 8.39MB
    u16* vt1l = vt1h + (size_t)B_ * H_ * KV_ * C_;
    u16* vt2h = (u16*)d_out;
    u16* vt2l = vt2h + (size_t)B_ * H_ * KV_ * C_;

    dim3 blk(256);
    dim3 gproj(C_ / 64, KV_ / 64, B_ * H_);            // (32,1,32)
    dim3 gout(B_ * C_ / 64, M_ / 64, 1);               // (64,16,1)
    dim3 gffn1(B_ * C_ / 64, F_ / 64, 1);              // (64,64,1)
    dim3 gffn2(B_ * C_ / 64, M_ / 64, 1);              // (64,16,1)
    dim3 gattn(B_ * H_ * (C_ / 64));                   // 1024
    dim3 gvt(C_ / 64, B_ * H_);                        // (32,32)
    dim3 gln(B_ * C_);                                 // 4096
    const long long AB = (long long)C_ * M_, BH = (long long)M_ * KV_, CZ = (long long)C_ * KV_;

    detect_dtype<<<1, 256, 0, stream>>>((const unsigned int*)wq1, fl);
    calibrate<<<1, 256, 0, stream>>>(cal);

    // ---- self-attention (masked) ----
    proj_qk64<0><<<gproj, blk, 0, stream>>>(x, wq1, q,  fl, cal, KV_, M_, AB, BH, CZ, H_);
    proj_qk64<0><<<gproj, blk, 0, stream>>>(x, wk1, kk, fl, cal, KV_, M_, AB, BH, CZ, H_);
    gemm_hilo<0,false,false><<<gproj, blk, 0, stream>>>(x, wv1, vv, nullptr, fl, KV_, M_, AB, BH, CZ, H_);
    v_to_bf16t<<<gvt, blk, 0, stream>>>(vv, vt1h, vt1l);
    attn_fast<<<gattn, blk, 0, stream>>>(q, kk, vt1h, vt1l, pre, cal, 1);
    attn_legacy<<<gattn, blk, 0, stream>>>(q, kk, vv, pre, cal, 1);
    gemm_hilo<1,false,false><<<gout, blk, 0, stream>>>(pre, wo1, attout, nullptr, fl, M_, M_, 0, 0, 0, 1);
    ln_f64<0, 0><<<gln, blk, 0, stream>>>(x, attout, g1, b1, n1, fl);

    // ---- cross-attention ----
    proj_qk64<1><<<gproj, blk, 0, stream>>>(n1, wq2, q,  fl, cal, KV_, M_, AB, BH, CZ, H_);
    proj_qk64<0><<<gproj, blk, 0, stream>>>(enc, wk2, kk, fl, cal, KV_, M_, AB, BH, CZ, H_);
    gemm_hilo<0,false,false><<<gproj, blk, 0, stream>>>(enc, wv2, vv, nullptr, fl, KV_, M_, AB, BH, CZ, H_);
    v_to_bf16t<<<gvt, blk, 0, stream>>>(vv, vt2h, vt2l);
    attn_fast<<<gattn, blk, 0, stream>>>(q, kk, vt2h, vt2l, pre, cal, 0);
    attn_legacy<<<gattn, blk, 0, stream>>>(q, kk, vv, pre, cal, 0);
    gemm_hilo<1,false,false><<<gout, blk, 0, stream>>>(pre, wo2, attout, nullptr, fl, M_, M_, 0, 0, 0, 1);
    ln_f64<1, 0><<<gln, blk, 0, stream>>>(n1, attout, g2, b2, n2, fl);   // in-place S4

    // ---- FFN (h1 fp32 spans S0..S3; ff in d_out; LN3 in-place) ----
    gemm_hilo<1,true,true><<<gffn1, blk, 0, stream>>>(n2, fw1, h1, fb1, fl, F_, M_, 0, 0, 0, 1);
    gemm_hilo<1,false,true><<<gffn2, blk, 0, stream>>>(h1, fw2, ff, fb2, fl, M_, F_, 0, 0, 0, 1);
    ln_f64<1, 1><<<gln, blk, 0, stream>>>(n2, ff, g3, b3, d_out, fl);
}

// Round 6
// 2526.869 us; speedup vs baseline: 1.2884x; 1.1487x over previous
//
#include <hip/hip_runtime.h>
#include <math.h>

// Problem dims (fixed)
#define B_ 2
#define C_ 2048
#define M_ 1024
#define H_ 16
#define KV_ 64
#define F_ 4096

typedef __attribute__((ext_vector_type(8))) __bf16 bf16x8;
typedef __attribute__((ext_vector_type(4))) float f32x4;
typedef unsigned short u16;

#if defined(__has_builtin)
#if __has_builtin(__builtin_amdgcn_mfma_f64_16x16x4f64)
#define HAVE_MFMA64 1
#endif
#endif
#ifndef HAVE_MFMA64
#define HAVE_MFMA64 0
#endif

#if HAVE_MFMA64
typedef __attribute__((ext_vector_type(4))) double f64x4;
#endif

__device__ __forceinline__ float bf2f(u16 u) {
    union { unsigned int i; float f; } x; x.i = ((unsigned int)u) << 16; return x.f;
}
__device__ __forceinline__ u16 f2bf(float f) {
    union { float f; unsigned int i; } x; x.f = f;
    unsigned int r = x.i + 0x7fffu + ((x.i >> 16) & 1u);
    return (u16)(r >> 16);
}
__device__ __forceinline__ float ldflag(const void* p, size_t i, int isf) {
    return isf ? ((const float*)p)[i] : bf2f(((const u16*)p)[i]);
}

__device__ __forceinline__ double blockReduceSumD(double v, double* red, int tid) {
#pragma unroll
    for (int off = 32; off > 0; off >>= 1) v += __shfl_down(v, off, 64);
    if ((tid & 63) == 0) red[tid >> 6] = v;
    __syncthreads();
    v = red[0] + red[1] + red[2] + red[3];
    __syncthreads();
    return v;
}

// ---------------------------------------------------------------------------
// Input-dtype detector (fires fp32 on this harness). flags[0]=1 iff fp32.
// ---------------------------------------------------------------------------
__global__ void detect_dtype(const unsigned int* __restrict__ w, int* __restrict__ flags) {
    __shared__ int cnt[256];
    int t = threadIdx.x, c = 0;
    for (int i = t; i < 2048; i += 256) {
        unsigned int e = (w[i] >> 7) & 0xffu;
        if (e >= 140u || (e > 0u && e < 91u)) c++;
    }
    cnt[t] = c; __syncthreads();
    for (int s = 128; s > 0; s >>= 1) { if (t < s) cnt[t] += cnt[t + s]; __syncthreads(); }
    if (t == 0) flags[0] = (cnt[0] > 300) ? 1 : 0;
}

// ---------------------------------------------------------------------------
// f64 MFMA self-calibration (round-2, HW-validated: cal[0]=1 on gfx950).
// cal[0] = 1 iff the fragment mapping was decoded AND end-to-end verified.
// cal[16 + lane*12 + {0..8}] = {am, ak, bn, bk, colD, rowD0..rowD3}.
// HW-measured (round 4): layout is NOT the standard CDNA map -- all
// consumers use the table only.
// ---------------------------------------------------------------------------
__device__ __forceinline__ float sAval(int m, int k) { return (float)(((m * 5 + k * 3) % 7) - 3); }
__device__ __forceinline__ float sBval(int k, int n) { return (float)(((k * 11 + n * 2) % 5) - 2); }
__device__ __forceinline__ float sQval(int m, int k) { return (float)(((m * 3 + k * 7) % 9) - 4); }
__device__ __forceinline__ float sKval(int c, int k) { return (float)(((c * 5 + k * 2) % 8) - 3); }

__global__ __launch_bounds__(256) void calibrate(int* __restrict__ cal) {
#if HAVE_MFMA64
    __shared__ int ctab[64][12];
    __shared__ int s_ok, s_bad;
    __shared__ float Ast[32][65], Bs[32][65];
    __shared__ float Qv[64][65], Kv[64][65];
    const int t = threadIdx.x;
    if (t == 0) { s_ok = 0; s_bad = 0; }
    __syncthreads();
    if (t < 64) {
        const int l = t;
        f64x4 z = {0.0, 0.0, 0.0, 0.0};
        f64x4 p1 = __builtin_amdgcn_mfma_f64_16x16x4f64(1.0, (double)l, z, 0, 0, 0);
        f64x4 p2 = __builtin_amdgcn_mfma_f64_16x16x4f64((double)l, 1.0, z, 0, 0, 0);
        int ok = 1, bFam = 0, aFam = 0;
        int colD[4], rowD[4];
#pragma unroll
        for (int r = 0; r < 4; r++) {
            double pv = p1[r];
            int f = 0, n = 0;
            if (pv >= 0.0 && pv <= 4096.0) {
                long long vi = (long long)(pv + 0.5);
                if (vi >= 96 && vi <= 156 && ((vi - 96) & 3) == 0) { f = 1; n = (int)((vi - 96) >> 2); }
                else if (vi >= 6 && vi <= 246 && ((vi - 6) & 15) == 0) { f = 2; n = (int)((vi - 6) >> 4); }
            }
            if (f == 0) ok = 0;
            if (r == 0) bFam = f; else if (f != bFam) ok = 0;
            colD[r] = n;
            pv = p2[r]; f = 0; n = 0;
            if (pv >= 0.0 && pv <= 4096.0) {
                long long wi = (long long)(pv + 0.5);
                if (wi >= 96 && wi <= 156 && ((wi - 96) & 3) == 0) { f = 1; n = (int)((wi - 96) >> 2); }
                else if (wi >= 6 && wi <= 246 && ((wi - 6) & 15) == 0) { f = 2; n = (int)((wi - 6) >> 4); }
            }
            if (f == 0) ok = 0;
            if (r == 0) aFam = f; else if (f != aFam) ok = 0;
            rowD[r] = n;
        }
        if (colD[1] != colD[0] || colD[2] != colD[0] || colD[3] != colD[0]) ok = 0;
        int rm = (1 << rowD[0]) | (1 << rowD[1]) | (1 << rowD[2]) | (1 << rowD[3]);
        if (__popc(rm) != 4) ok = 0;
        int cm = 1 << colD[0];
#pragma unroll
        for (int off = 1; off < 16; off <<= 1) {
#pragma unroll
            for (int r = 0; r < 4; r++)
                if (__shfl_xor(rowD[r], off, 64) != rowD[r]) ok = 0;
            cm |= __shfl_xor(cm, off, 64);
        }
        if (cm != 0xffff) ok = 0;
        const int am = (aFam == 2) ? (l >> 2) : (l & 15);
        const int ak = (aFam == 2) ? (l & 3) : (l >> 4);
        const int bn = (bFam == 2) ? (l >> 2) : (l & 15);
        const int bk = (bFam == 2) ? (l & 3) : (l >> 4);
        // probe 3: exact end-to-end check of the decoded mapping
        {
            double a3 = (double)sAval(am, ak);
            double b3 = (double)sBval(bk, bn);
            f64x4 p3 = __builtin_amdgcn_mfma_f64_16x16x4f64(a3, b3, z, 0, 0, 0);
#pragma unroll
            for (int r = 0; r < 4; r++) {
                double ref = 0.0;
                for (int k2 = 0; k2 < 4; k2++)
                    ref += (double)sAval(rowD[r], k2) * (double)sBval(k2, colD[0]);
                if (p3[r] != ref) ok = 0;
            }
        }
        unsigned long long bb = __ballot(ok != 0);
        ctab[l][0] = am; ctab[l][1] = ak; ctab[l][2] = bn; ctab[l][3] = bk;
        ctab[l][4] = colD[0];
        ctab[l][5] = rowD[0]; ctab[l][6] = rowD[1]; ctab[l][7] = rowD[2]; ctab[l][8] = rowD[3];
        ctab[l][9] = 0; ctab[l][10] = 0; ctab[l][11] = 0;
        if (l == 0) s_ok = (bb == ~0ull) ? 1 : 0;
    }
    __syncthreads();
    // synthetic tiles for the structural verification
    for (int i = t; i < 32 * 64; i += 256) {
        int k2 = i >> 6, m2 = i & 63;
        Ast[k2][m2] = sAval(m2, k2);
        Bs[k2][m2] = sBval(k2, m2);
    }
    for (int i = t; i < 64 * 64; i += 256) {
        int r2 = i >> 6, c2 = i & 63;
        Qv[r2][c2] = sQval(r2, c2);
        Kv[r2][c2] = sKval(r2, c2);
    }
    __syncthreads();
    if (s_ok) {
        const int w = t >> 6;
        const int* cl = ctab[t & 63];
        const int am = cl[0], ak2 = cl[1], bn2 = cl[2], bk2 = cl[3], cD = cl[4];
        const int rd[4] = {cl[5], cl[6], cl[7], cl[8]};
        int ok = 1;
        // proj-pattern: D = A(64x32) * B(32x64)
        {
            f64x4 acc4[4] = { {0,0,0,0},{0,0,0,0},{0,0,0,0},{0,0,0,0} };
#pragma unroll
            for (int ks = 0; ks < 8; ks++) {
                double ad = (double)Ast[4 * ks + ak2][16 * w + am];
#pragma unroll
                for (int nt = 0; nt < 4; nt++) {
                    double bd = (double)Bs[4 * ks + bk2][16 * nt + bn2];
                    acc4[nt] = __builtin_amdgcn_mfma_f64_16x16x4f64(ad, bd, acc4[nt], 0, 0, 0);
                }
            }
#pragma unroll
            for (int nt = 0; nt < 4; nt++)
#pragma unroll
                for (int i = 0; i < 4; i++) {
                    int row = 16 * w + rd[i], col = 16 * nt + cD;
                    double ref = 0.0;
                    for (int k2 = 0; k2 < 32; k2++)
                        ref += (double)sAval(row, k2) * (double)sBval(k2, col);
                    if (acc4[nt][i] != ref) ok = 0;
                }
        }
        // attn-pattern: S = Q(16-strip) K^T with K staged [c][k]
        {
            double aqv[16];
#pragma unroll
            for (int ks = 0; ks < 16; ks++)
                aqv[ks] = (double)Qv[16 * w + am][4 * ks + ak2];
            f64x4 S[4] = { {0,0,0,0},{0,0,0,0},{0,0,0,0},{0,0,0,0} };
#pragma unroll
            for (int ks = 0; ks < 16; ks++) {
#pragma unroll
                for (int nt = 0; nt < 4; nt++) {
                    double bd = (double)Kv[16 * nt + bn2][4 * ks + bk2];
                    S[nt] = __builtin_amdgcn_mfma_f64_16x16x4f64(aqv[ks], bd, S[nt], 0, 0, 0);
                }
            }
#pragma unroll
            for (int nt = 0; nt < 4; nt++)
#pragma unroll
                for (int i = 0; i < 4; i++) {
                    int row = 16 * w + rd[i], col = 16 * nt + cD;
                    double ref = 0.0;
                    for (int k2 = 0; k2 < 64; k2++)
                        ref += (double)sQval(row, k2) * (double)sKval(col, k2);
                    if (S[nt][i] != ref) ok = 0;
                }
        }
        if (!ok) s_bad = 1;
    }
    __syncthreads();
    if (t < 64) {
#pragma unroll
        for (int j = 0; j < 12; j++) cal[16 + t * 12 + j] = ctab[t][j];
    }
    if (t == 0) cal[0] = (s_ok && !s_bad) ? 1 : 0;
#else
    if (threadIdx.x == 0) cal[0] = 0;
#endif
}

// ---------------------------------------------------------------------------
// V pre-transpose: vv [bh][c][v] fp32 -> hi/lo bf16 split, layout [bh][v][C].
// ---------------------------------------------------------------------------
__global__ __launch_bounds__(256) void v_to_bf16t(
    const float* __restrict__ vv, u16* __restrict__ hi, u16* __restrict__ lo)
{
    __shared__ float Ls[64][65];
    const int bh = blockIdx.y, c0 = blockIdx.x * 64;
    const int t = threadIdx.x;
    const int c = t >> 2, vb = (t & 3) * 16;
    const float* src = vv + ((size_t)bh * C_ + c0 + c) * KV_ + vb;
#pragma unroll
    for (int i = 0; i < 4; i++) {
        float4 p = *(const float4*)(src + 4 * i);
        Ls[vb + 4*i + 0][c] = p.x;
        Ls[vb + 4*i + 1][c] = p.y;
        Ls[vb + 4*i + 2][c] = p.z;
        Ls[vb + 4*i + 3][c] = p.w;
    }
    __syncthreads();
#pragma unroll
    for (int it = 0; it < 2; it++) {
        int idx = t + 256 * it;            // 0..511 : 64 rows x 8 chunks
        int v = idx >> 3, ch = idx & 7;
        u16 h8[8], l8[8];
#pragma unroll
        for (int j = 0; j < 8; j++) {
            float x = Ls[v][ch * 8 + j];
            h8[j] = f2bf(x);
            l8[j] = f2bf(x - bf2f(h8[j]));
        }
        size_t off = ((size_t)bh * KV_ + v) * C_ + c0 + ch * 8;
        int4 hp, lp;
        hp.x = (int)((unsigned)h8[0] | ((unsigned)h8[1] << 16));
        hp.y = (int)((unsigned)h8[2] | ((unsigned)h8[3] << 16));
        hp.z = (int)((unsigned)h8[4] | ((unsigned)h8[5] << 16));
        hp.w = (int)((unsigned)h8[6] | ((unsigned)h8[7] << 16));
        lp.x = (int)((unsigned)l8[0] | ((unsigned)l8[1] << 16));
        lp.y = (int)((unsigned)l8[2] | ((unsigned)l8[3] << 16));
        lp.z = (int)((unsigned)l8[4] | ((unsigned)l8[5] << 16));
        lp.w = (int)((unsigned)l8[6] | ((unsigned)l8[7] << 16));
        *(int4*)(hi + off) = hp;
        *(int4*)(lo + off) = lp;
    }
}

// ---------------------------------------------------------------------------
// Q/K projection GEMM: fp64 ACCUMULATION, fp32 LDS tiles. (round-5, passing)
// ---------------------------------------------------------------------------
template<int AMODE>
__global__ __launch_bounds__(256) void proj_qk64(
    const void* __restrict__ Ab, const void* __restrict__ Bb,
    float* __restrict__ Cb, const int* __restrict__ flags,
    const int* __restrict__ cal,
    int N, int Kd, long long a_bstr, long long b_hstr, long long c_zstr, int NH)
{
    const int isf = flags[0];
    const int isfA = (AMODE == 1) ? 1 : isf;
    __shared__ float Ast[32][65];   // [k][m]
    __shared__ float Bs[32][65];    // [k][n]
    const int t = threadIdx.x;
    const int m0 = blockIdx.x * 64, n0 = blockIdx.y * 64;
    const int zb = blockIdx.z / NH, zh = blockIdx.z % NH;
    const size_t aoff = (size_t)zb * a_bstr, boff = (size_t)zh * b_hstr;
    const size_t czoff = (size_t)blockIdx.z * c_zstr;
    const int ar = t >> 2, ak = (t & 3) * 8;
    const int bk = t >> 3, bn = (t & 7) * 8;
    const int cok = cal[0];

#if HAVE_MFMA64
    if (cok) {
        const int* cl = cal + 16 + (t & 63) * 12;
        const int am = cl[0], ak2 = cl[1], bn2 = cl[2], bk2 = cl[3], cD = cl[4];
        const int rd[4] = {cl[5], cl[6], cl[7], cl[8]};
        const int w = t >> 6;
        f64x4 acc4[4] = { {0,0,0,0},{0,0,0,0},{0,0,0,0},{0,0,0,0} };
        for (int k0 = 0; k0 < Kd; k0 += 32) {
            float av[8];
            {
                size_t off = aoff + (size_t)(m0 + ar) * Kd + k0 + ak;
                if (isfA) {
                    const float* ap = (const float*)Ab + off;
                    float4 p0 = *(const float4*)ap, p1 = *((const float4*)ap + 1);
                    av[0]=p0.x; av[1]=p0.y; av[2]=p0.z; av[3]=p0.w;
                    av[4]=p1.x; av[5]=p1.y; av[6]=p1.z; av[7]=p1.w;
                } else {
                    const u16* ap = (const u16*)Ab + off;
                    int4 p = *(const int4*)ap;
                    unsigned int u[4] = {(unsigned)p.x,(unsigned)p.y,(unsigned)p.z,(unsigned)p.w};
#pragma unroll
                    for (int j = 0; j < 4; j++) {
                        av[2*j]   = bf2f((u16)(u[j] & 0xffffu));
                        av[2*j+1] = bf2f((u16)(u[j] >> 16));
                    }
                }
            }
#pragma unroll
            for (int j = 0; j < 8; j++) Ast[ak + j][ar] = av[j];
            float bv[8];
            {
                size_t off = boff + (size_t)(k0 + bk) * N + n0 + bn;
                if (isf) {
                    const float* bp = (const float*)Bb + off;
                    float4 p0 = *(const float4*)bp, p1 = *((const float4*)bp + 1);
                    bv[0]=p0.x; bv[1]=p0.y; bv[2]=p0.z; bv[3]=p0.w;
                    bv[4]=p1.x; bv[5]=p1.y; bv[6]=p1.z; bv[7]=p1.w;
                } else {
                    const u16* bp = (const u16*)Bb + off;
                    int4 p = *(const int4*)bp;
                    unsigned int u[4] = {(unsigned)p.x,(unsigned)p.y,(unsigned)p.z,(unsigned)p.w};
#pragma unroll
                    for (int j = 0; j < 4; j++) {
                        bv[2*j]   = bf2f((u16)(u[j] & 0xffffu));
                        bv[2*j+1] = bf2f((u16)(u[j] >> 16));
                    }
                }
            }
#pragma unroll
            for (int j = 0; j < 8; j++) Bs[bk][bn + j] = bv[j];
            __syncthreads();
#pragma unroll
            for (int ks = 0; ks < 8; ks++) {
                double ad = (double)Ast[4 * ks + ak2][16 * w + am];
#pragma unroll
                for (int nt = 0; nt < 4; nt++) {
                    double bd = (double)Bs[4 * ks + bk2][16 * nt + bn2];
                    acc4[nt] = __builtin_amdgcn_mfma_f64_16x16x4f64(ad, bd, acc4[nt], 0, 0, 0);
                }
            }
            __syncthreads();
        }
#pragma unroll
        for (int nt = 0; nt < 4; nt++)
#pragma unroll
            for (int i = 0; i < 4; i++)
                Cb[czoff + (size_t)(m0 + 16 * w + rd[i]) * N + n0 + 16 * nt + cD] =
                    (float)acc4[nt][i];
        return;
    }
#endif
    // ---- legacy scalar-fp64 path (round-0, passing) ----
    double acc[4][4] = {};
    for (int k0 = 0; k0 < Kd; k0 += 32) {
        float av[8];
        {
            size_t off = aoff + (size_t)(m0 + ar) * Kd + k0 + ak;
            if (isfA) {
                const float* ap = (const float*)Ab + off;
                float4 p0 = *(const float4*)ap, p1 = *((const float4*)ap + 1);
                av[0]=p0.x; av[1]=p0.y; av[2]=p0.z; av[3]=p0.w;
                av[4]=p1.x; av[5]=p1.y; av[6]=p1.z; av[7]=p1.w;
            } else {
                const u16* ap = (const u16*)Ab + off;
                int4 p = *(const int4*)ap;
                unsigned int u[4] = {(unsigned)p.x,(unsigned)p.y,(unsigned)p.z,(unsigned)p.w};
#pragma unroll
                for (int j = 0; j < 4; j++) {
                    av[2*j]   = bf2f((u16)(u[j] & 0xffffu));
                    av[2*j+1] = bf2f((u16)(u[j] >> 16));
                }
            }
        }
#pragma unroll
        for (int j = 0; j < 8; j++) Ast[ak + j][ar] = av[j];
        float bv[8];
        {
            size_t off = boff + (size_t)(k0 + bk) * N + n0 + bn;
            if (isf) {
                const float* bp = (const float*)Bb + off;
                float4 p0 = *(const float4*)bp, p1 = *((const float4*)bp + 1);
                bv[0]=p0.x; bv[1]=p0.y; bv[2]=p0.z; bv[3]=p0.w;
                bv[4]=p1.x; bv[5]=p1.y; bv[6]=p1.z; bv[7]=p1.w;
            } else {
                const u16* bp = (const u16*)Bb + off;
                int4 p = *(const int4*)bp;
                unsigned int u[4] = {(unsigned)p.x,(unsigned)p.y,(unsigned)p.z,(unsigned)p.w};
#pragma unroll
                for (int j = 0; j < 4; j++) {
                    bv[2*j]   = bf2f((u16)(u[j] & 0xffffu));
                    bv[2*j+1] = bf2f((u16)(u[j] >> 16));
                }
            }
        }
#pragma unroll
        for (int j = 0; j < 8; j++) Bs[bk][bn + j] = bv[j];
        __syncthreads();
        const int r0 = (t & 15) * 4, c0 = (t >> 4) * 4;
#pragma unroll
        for (int kk = 0; kk < 32; kk++) {
            float4 a4 = *(const float4*)&Ast[kk][r0];
            float4 b4 = *(const float4*)&Bs[kk][c0];
            double a0=a4.x, a1=a4.y, a2=a4.z, a3=a4.w;
            double b0=b4.x, b1=b4.y, b2=b4.z, b3=b4.w;
            acc[0][0] += a0*b0; acc[0][1] += a0*b1; acc[0][2] += a0*b2; acc[0][3] += a0*b3;
            acc[1][0] += a1*b0; acc[1][1] += a1*b1; acc[1][2] += a1*b2; acc[1][3] += a1*b3;
            acc[2][0] += a2*b0; acc[2][1] += a2*b1; acc[2][2] += a2*b2; acc[2][3] += a2*b3;
            acc[3][0] += a3*b0; acc[3][1] += a3*b1; acc[3][2] += a3*b2; acc[3][3] += a3*b3;
        }
        __syncthreads();
    }
    {
        const int r0 = (t & 15) * 4, c0 = (t >> 4) * 4;
#pragma unroll
        for (int i = 0; i < 4; i++)
#pragma unroll
            for (int j = 0; j < 4; j++)
                Cb[czoff + (size_t)(m0 + r0 + i) * N + n0 + c0 + j] = (float)acc[i][j];
    }
}

// ---------------------------------------------------------------------------
// MFMA GEMM with bf16 hi/lo 3-term split (post-softmax ops).
// ROUND-6 CHANGE: B-tile column XOR-swizzle. The old b_hi[n][k] layout with
// 40-u16 rows put all 64 lanes' scalar B-staging writes (fixed j) on ~4
// banks (20*bn8 % 32 == 0 for bn8 multiple of 8) -> ~16-way conflict, the
// dominant LDS cost of every GEMM dispatch. Storing (n,k) at column
// k ^ (((n>>3)&3)<<3) spreads writes to ~2-way; the flip is 8-aligned so
// b128 fragment reads at base (quad*8)^flip stay 16B-aligned and return
// k = quad*8..+7 in order. Pure layout permutation -- bit-identical math.
// ---------------------------------------------------------------------------
template<int AMODE, bool RELU, bool BIAS>
__global__ __launch_bounds__(256) void gemm_hilo(
    const void* __restrict__ Ab, const void* __restrict__ Bb,
    float* __restrict__ Cb, const void* __restrict__ bias,
    const int* __restrict__ flags,
    int N, int Kd, long long a_bstr, long long b_hstr, long long c_zstr, int NH)
{
    const int isf = flags[0];
    const int aIsF32 = (AMODE == 1) ? 1 : isf;
    __shared__ u16 a_hi[64][40], a_lo[64][40];
    __shared__ u16 b_hi[64][40], b_lo[64][40];

    const int tid = threadIdx.x;
    const int w = tid >> 6, l = tid & 63;
    const int lq = l & 15, quad = l >> 4;
    const int m0 = blockIdx.x * 64, n0 = blockIdx.y * 64;
    const int zb = blockIdx.z / NH, zh = blockIdx.z % NH;
    const size_t aoff = (size_t)zb * a_bstr, boff = (size_t)zh * b_hstr;

    f32x4 acc[4] = { {0,0,0,0},{0,0,0,0},{0,0,0,0},{0,0,0,0} };
    const int arow = tid >> 2, ac8 = (tid & 3) * 8;
    const int bk = tid >> 3, bn8 = (tid & 7) * 8;
    const int bflip = (tid & 3) << 3;            // = ((n>>3)&3)<<3 for n=bn8+j, j<8

    for (int k0 = 0; k0 < Kd; k0 += 32) {
        {
            size_t off = aoff + (size_t)(m0 + arow) * Kd + k0 + ac8;
            u16 hh[8], ll[8];
            if (aIsF32) {
                const float* ap = (const float*)Ab + off;
                float4 p0 = *(const float4*)ap, p1 = *((const float4*)ap + 1);
                float vv[8] = {p0.x,p0.y,p0.z,p0.w,p1.x,p1.y,p1.z,p1.w};
#pragma unroll
                for (int j = 0; j < 8; j++) {
                    hh[j] = f2bf(vv[j]);
                    ll[j] = f2bf(vv[j] - bf2f(hh[j]));
                }
            } else {
                int4 p = *(const int4*)((const u16*)Ab + off);
                unsigned int u[4] = {(unsigned)p.x,(unsigned)p.y,(unsigned)p.z,(unsigned)p.w};
#pragma unroll
                for (int j = 0; j < 4; j++) {
                    hh[2*j]   = (u16)(u[j] & 0xffffu);
                    hh[2*j+1] = (u16)(u[j] >> 16);
                    ll[2*j] = 0; ll[2*j+1] = 0;
                }
            }
            int4 ph, pl;
            ph.x = (int)((unsigned)hh[0] | ((unsigned)hh[1] << 16));
            ph.y = (int)((unsigned)hh[2] | ((unsigned)hh[3] << 16));
            ph.z = (int)((unsigned)hh[4] | ((unsigned)hh[5] << 16));
            ph.w = (int)((unsigned)hh[6] | ((unsigned)hh[7] << 16));
            pl.x = (int)((unsigned)ll[0] | ((unsigned)ll[1] << 16));
            pl.y = (int)((unsigned)ll[2] | ((unsigned)ll[3] << 16));
            pl.z = (int)((unsigned)ll[4] | ((unsigned)ll[5] << 16));
            pl.w = (int)((unsigned)ll[6] | ((unsigned)ll[7] << 16));
            *(int4*)&a_hi[arow][ac8] = ph;
            *(int4*)&a_lo[arow][ac8] = pl;
        }
        {
            size_t off = boff + (size_t)(k0 + bk) * N + n0 + bn8;
            u16 hh[8], ll[8];
            if (isf) {
                const float* bp = (const float*)Bb + off;
                float4 p0 = *(const float4*)bp, p1 = *((const float4*)bp + 1);
                float vv[8] = {p0.x,p0.y,p0.z,p0.w,p1.x,p1.y,p1.z,p1.w};
#pragma unroll
                for (int j = 0; j < 8; j++) {
                    hh[j] = f2bf(vv[j]);
                    ll[j] = f2bf(vv[j] - bf2f(hh[j]));
                }
            } else {
                int4 p = *(const int4*)((const u16*)Bb + off);
                unsigned int u[4] = {(unsigned)p.x,(unsigned)p.y,(unsigned)p.z,(unsigned)p.w};
#pragma unroll
                for (int j = 0; j < 4; j++) {
                    hh[2*j]   = (u16)(u[j] & 0xffffu);
                    hh[2*j+1] = (u16)(u[j] >> 16);
                    ll[2*j] = 0; ll[2*j+1] = 0;
                }
            }
            const int bkc = bk ^ bflip;          // swizzled k-column
#pragma unroll
            for (int j = 0; j < 8; j++) {
                b_hi[bn8 + j][bkc] = hh[j];
                b_lo[bn8 + j][bkc] = ll[j];
            }
        }
        __syncthreads();
        bf16x8 ah = *(bf16x8*)&a_hi[w * 16 + lq][quad * 8];
        bf16x8 al = *(bf16x8*)&a_lo[w * 16 + lq][quad * 8];
#pragma unroll
        for (int nt = 0; nt < 4; nt++) {
            const int bcol = (quad * 8) ^ (((2 * nt + (lq >> 3)) & 3) << 3);
            bf16x8 bh = *(bf16x8*)&b_hi[nt * 16 + lq][bcol];
            bf16x8 bl = *(bf16x8*)&b_lo[nt * 16 + lq][bcol];
            acc[nt] = __builtin_amdgcn_mfma_f32_16x16x32_bf16(ah, bh, acc[nt], 0, 0, 0);
            acc[nt] = __builtin_amdgcn_mfma_f32_16x16x32_bf16(ah, bl, acc[nt], 0, 0, 0);
            acc[nt] = __builtin_amdgcn_mfma_f32_16x16x32_bf16(al, bh, acc[nt], 0, 0, 0);
        }
        __syncthreads();
    }

    const int rowb = m0 + w * 16 + quad * 4;
    const size_t czoff = (size_t)blockIdx.z * c_zstr;
#pragma unroll
    for (int nt = 0; nt < 4; nt++) {
        int col = n0 + nt * 16 + lq;
        float bv = BIAS ? ldflag(bias, col, isf) : 0.0f;
#pragma unroll
        for (int r = 0; r < 4; r++) {
            float val = acc[nt][r] + bv;
            if (RELU) val = fmaxf(val, 0.0f);
            Cb[czoff + (size_t)(rowb + r) * N + col] = val;
        }
    }
}

// ---------------------------------------------------------------------------
// FAST attention (round-5, passing): f64 QK^T (calibrated table) + PV on the
// bf16 matrix pipe. Unchanged.
// ---------------------------------------------------------------------------
__global__ __launch_bounds__(256) void attn_fast(
    const float* __restrict__ q, const float* __restrict__ k,
    const u16* __restrict__ vthi, const u16* __restrict__ vtlo,
    float* __restrict__ pre,
    const int* __restrict__ cal, int masked)
{
#if HAVE_MFMA64
    __shared__ float Ks[64][68];          // Q staging, then K tile [c][k]
    __shared__ u16 VtH[64][68];           // V^T hi tile [v][c]
    __shared__ u16 VtL[64][68];           // V^T lo tile [v][c]
    __shared__ u16 Pslab[4][2][16][68];   // [wave][hi/lo][q-row][c]
    __shared__ float alphaT[64];          // per-row alpha (this tile)
    __shared__ float lT[64];              // per-row l (epilogue)

    if (cal[0] == 0) return;

    const int idx = blockIdx.x;
    const int q0 = (idx & (C_ / 64 - 1)) * 64;
    const int h = (idx >> 5) & (H_ - 1);
    const int b = idx >> 9;
    const size_t bh = (size_t)(b * H_ + h);
    const float* Qg = q + (bh * C_ + q0) * KV_;
    const float* Kg = k + bh * C_ * KV_;
    const u16* vthg = vthi + bh * (size_t)KV_ * C_;
    const u16* vtlg = vtlo + bh * (size_t)KV_ * C_;

    const int t = threadIdx.x;
    const int* cl = cal + 16 + (t & 63) * 12;
    const int am = cl[0], ak2 = cl[1], bn2 = cl[2], bk2 = cl[3], cD = cl[4];
    const int rdv[4] = {cl[5], cl[6], cl[7], cl[8]};
    const int w = t >> 6, l15 = t & 15, g = (t >> 4) & 3;
    const int srow = t >> 2, sc = (t & 3) * 16;

    {   // stage Q [q][k]
        const float* src = Qg + (size_t)srow * KV_ + sc;
#pragma unroll
        for (int i = 0; i < 4; i++)
            *(float4*)&Ks[srow][sc + 4 * i] = *(const float4*)(src + 4 * i);
    }
    __syncthreads();
    double aq[16];
#pragma unroll
    for (int ks = 0; ks < 16; ks++)
        aq[ks] = (double)Ks[16 * w + am][4 * ks + ak2];

    f32x4 acc[4] = { {0,0,0,0},{0,0,0,0},{0,0,0,0},{0,0,0,0} };
    float mreg[4] = {-3.0e38f, -3.0e38f, -3.0e38f, -3.0e38f};
    float lreg[4] = {0.0f, 0.0f, 0.0f, 0.0f};

    for (int kt = 0; kt < 32; kt++) {
        const int c0 = kt * 64;
        __syncthreads();   // prev tile (and aq reads at kt=0) fully consumed
        {   // stage K fp32 [c][k]
            const float* ksrc = Kg + (size_t)(c0 + srow) * KV_ + sc;
#pragma unroll
            for (int i = 0; i < 4; i++)
                *(float4*)&Ks[srow][sc + 4 * i] = *(const float4*)(ksrc + 4 * i);
        }
        // stage Vt hi/lo tiles (B-frag-ready rows, contiguous in keys)
#pragma unroll
        for (int it = 0; it < 4; it++) {
            int idx2 = t + 256 * it;
            int arr = idx2 >> 9, rem = idx2 & 511;
            int vrow = rem >> 3, ch = rem & 7;
            const u16* gsrc = (arr ? vtlg : vthg) + (size_t)vrow * C_ + c0 + ch * 8;
            u16* dst = (arr ? &VtL[vrow][ch * 8] : &VtH[vrow][ch * 8]);
            int4 d = *(const int4*)gsrc;
            *(int2*)dst = make_int2(d.x, d.y);
            *(int2*)(dst + 4) = make_int2(d.z, d.w);
        }
        __syncthreads();

        // S strip (16 q x 64 keys) in fp64 on the matrix pipe
        f64x4 S[4] = { {0,0,0,0},{0,0,0,0},{0,0,0,0},{0,0,0,0} };
#pragma unroll
        for (int ks = 0; ks < 16; ks++) {
#pragma unroll
            for (int nt = 0; nt < 4; nt++) {
                double bd = (double)Ks[16 * nt + bn2][4 * ks + bk2];
                S[nt] = __builtin_amdgcn_mfma_f64_16x16x4f64(aq[ks], bd, S[nt], 0, 0, 0);
            }
        }
        if (masked) {
#pragma unroll
            for (int nt = 0; nt < 4; nt++) {
                const int cg = c0 + 16 * nt + cD;
#pragma unroll
                for (int i = 0; i < 4; i++)
                    if (cg <= q0 + 16 * w + rdv[i]) S[nt][i] -= 100.0;
            }
        }
        // wave-local online softmax on f64-rows rdv[i] (uniform per group)
        float tm[4];
#pragma unroll
        for (int i = 0; i < 4; i++)
            tm[i] = fmaxf(fmaxf((float)S[0][i], (float)S[1][i]),
                          fmaxf((float)S[2][i], (float)S[3][i]));
#pragma unroll
        for (int off = 1; off < 16; off <<= 1)
#pragma unroll
            for (int i = 0; i < 4; i++)
                tm[i] = fmaxf(tm[i], __shfl_xor(tm[i], off, 64));
        float alpha[4];
#pragma unroll
        for (int i = 0; i < 4; i++) {
            const float mo = mreg[i];
            const float mn = fmaxf(mo, tm[i]);
            alpha[i] = (mo < -1.0e37f) ? 0.0f : __expf(0.125f * (mo - mn));
            mreg[i] = mn;
        }
        if (l15 == 0) {
#pragma unroll
            for (int i = 0; i < 4; i++) alphaT[16 * w + rdv[i]] = alpha[i];
        }
        // P = exp(0.125(S-m)) -> bf16 hi/lo slab at row rdv[i], col 16nt+cD
        float ts[4] = {0.0f, 0.0f, 0.0f, 0.0f};
#pragma unroll
        for (int nt = 0; nt < 4; nt++) {
#pragma unroll
            for (int i = 0; i < 4; i++) {
                float p = __expf((float)(0.125 * (S[nt][i] - (double)mreg[i])));
                ts[i] += p;
                u16 ph = f2bf(p);
                u16 pl = f2bf(p - bf2f(ph));
                Pslab[w][0][rdv[i]][16 * nt + cD] = ph;
                Pslab[w][1][rdv[i]][16 * nt + cD] = pl;
            }
        }
#pragma unroll
        for (int off = 1; off < 16; off <<= 1)
#pragma unroll
            for (int i = 0; i < 4; i++)
                ts[i] += __shfl_xor(ts[i], off, 64);
#pragma unroll
        for (int i = 0; i < 4; i++)
            lreg[i] = lreg[i] * alpha[i] + ts[i];

        // wave-internal LDS write->read fence (cross-lane, same wave)
        __builtin_amdgcn_sched_barrier(0);
        asm volatile("s_waitcnt lgkmcnt(0)" ::: "memory");
        __builtin_amdgcn_sched_barrier(0);

        // re-index alpha to bf16-D rows 4g+i, rescale accumulators
        float af[4];
#pragma unroll
        for (int i = 0; i < 4; i++) af[i] = alphaT[16 * w + 4 * g + i];
#pragma unroll
        for (int nt = 0; nt < 4; nt++)
#pragma unroll
            for (int i = 0; i < 4; i++) acc[nt][i] *= af[i];

        // PV on the bf16 matrix pipe: 3-term hi/lo, 2 x K=32 steps
        union F8 { struct { int2 a, b; } p; bf16x8 v; };
#pragma unroll
        for (int ks2 = 0; ks2 < 2; ks2++) {
            const u16* pa = &Pslab[w][0][l15][8 * g + 32 * ks2];
            const u16* pb = &Pslab[w][1][l15][8 * g + 32 * ks2];
            F8 pah, pal;
            pah.p.a = *(const int2*)pa; pah.p.b = *(const int2*)(pa + 4);
            pal.p.a = *(const int2*)pb; pal.p.b = *(const int2*)(pb + 4);
#pragma unroll
            for (int nt = 0; nt < 4; nt++) {
                const u16* vh = &VtH[16 * nt + l15][8 * g + 32 * ks2];
                const u16* vl = &VtL[16 * nt + l15][8 * g + 32 * ks2];
                F8 vbh, vbl;
                vbh.p.a = *(const int2*)vh; vbh.p.b = *(const int2*)(vh + 4);
                vbl.p.a = *(const int2*)vl; vbl.p.b = *(const int2*)(vl + 4);
                acc[nt] = __builtin_amdgcn_mfma_f32_16x16x32_bf16(pah.v, vbh.v, acc[nt], 0, 0, 0);
                acc[nt] = __builtin_amdgcn_mfma_f32_16x16x32_bf16(pah.v, vbl.v, acc[nt], 0, 0, 0);
                acc[nt] = __builtin_amdgcn_mfma_f32_16x16x32_bf16(pal.v, vbh.v, acc[nt], 0, 0, 0);
            }
        }
    }
    // epilogue: re-index l to bf16-D rows; out = O / l; pre [B, C, H, V]
    if (l15 == 0) {
#pragma unroll
        for (int i = 0; i < 4; i++) lT[16 * w + rdv[i]] = lreg[i];
    }
    __builtin_amdgcn_sched_barrier(0);
    asm volatile("s_waitcnt lgkmcnt(0)" ::: "memory");
    __builtin_amdgcn_sched_barrier(0);
#pragma unroll
    for (int i = 0; i < 4; i++) {
        const float li = lT[16 * w + 4 * g + i];
        const size_t rbase = (((size_t)b * C_ + q0 + 16 * w + 4 * g + i) * H_ + h) * KV_;
#pragma unroll
        for (int nt = 0; nt < 4; nt++)
            pre[rbase + 16 * nt + l15] = acc[nt][i] / li;
    }
#endif
}

// ---------------------------------------------------------------------------
// LEGACY attention (round-0, passing, scalar fp64). Runs iff cal[0]==0.
// ---------------------------------------------------------------------------
__global__ __launch_bounds__(256) void attn_legacy(
    const float* __restrict__ q, const float* __restrict__ k,
    const float* __restrict__ v, float* __restrict__ pre,
    const int* __restrict__ cal, int masked)
{
    __shared__ float Qs[64][68];
    __shared__ float KPs[64][68];
    __shared__ float Vs[64][68];
    __shared__ float redm[64][17];
    __shared__ float redl[64][17];
    __shared__ float mrow[64], lrow[64], arow[64];

    if (cal[0] != 0) return;

    const int idx = blockIdx.x;
    const int q0 = (idx & (C_ / 64 - 1)) * 64;
    const int h = (idx >> 5) & (H_ - 1);
    const int b = idx >> 9;
    const size_t bh = (size_t)(b * H_ + h);
    const float* Qg = q + (bh * C_ + q0) * KV_;
    const float* Kg = k + bh * C_ * KV_;
    const float* Vg = v + bh * C_ * KV_;
    const int t = threadIdx.x;
    const int tq = t & 15, tc = t >> 4;
    const int srow = t >> 2, scol = (t & 3) * 16;

    {
        const float* src = Qg + (size_t)srow * KV_ + scol;
#pragma unroll
        for (int i = 0; i < 4; i++) {
            float4 p4 = *(const float4*)(src + 4 * i);
            Qs[scol + 4*i + 0][srow] = p4.x;
            Qs[scol + 4*i + 1][srow] = p4.y;
            Qs[scol + 4*i + 2][srow] = p4.z;
            Qs[scol + 4*i + 3][srow] = p4.w;
        }
    }
    if (t < 64) { mrow[t] = -3.0e38f; lrow[t] = 0.0f; }

    float O[4][4] = {};

    for (int kt = 0; kt < 32; kt++) {
        const int c0 = kt * 64;
        __syncthreads();
        {
            const float* ksrc = Kg + (size_t)(c0 + srow) * KV_ + scol;
#pragma unroll
            for (int i = 0; i < 4; i++) {
                float4 p4 = *(const float4*)(ksrc + 4 * i);
                KPs[scol + 4*i + 0][srow] = p4.x;
                KPs[scol + 4*i + 1][srow] = p4.y;
                KPs[scol + 4*i + 2][srow] = p4.z;
                KPs[scol + 4*i + 3][srow] = p4.w;
            }
            const float* vsrc = Vg + (size_t)(c0 + srow) * KV_ + scol;
#pragma unroll
            for (int i = 0; i < 4; i++)
                *(float4*)&Vs[srow][scol + 4 * i] = *(const float4*)(vsrc + 4 * i);
        }
        __syncthreads();

        double Sd[4][4] = {};
#pragma unroll 4
        for (int j = 0; j < 64; j++) {
            float4 qa = *(const float4*)&Qs[j][4 * tq];
            float4 kb = *(const float4*)&KPs[j][4 * tc];
            double qd[4] = {qa.x, qa.y, qa.z, qa.w};
            double kd[4] = {kb.x, kb.y, kb.z, kb.w};
#pragma unroll
            for (int i = 0; i < 4; i++)
#pragma unroll
                for (int jj = 0; jj < 4; jj++)
                    Sd[i][jj] += qd[i] * kd[jj];
        }
        if (masked) {
#pragma unroll
            for (int i = 0; i < 4; i++)
#pragma unroll
                for (int jj = 0; jj < 4; jj++)
                    if (c0 + 4 * tc + jj <= q0 + 4 * tq + i) Sd[i][jj] -= 100.0;
        }
#pragma unroll
        for (int i = 0; i < 4; i++) {
            double mm = fmax(fmax(Sd[i][0], Sd[i][1]), fmax(Sd[i][2], Sd[i][3]));
            redm[4 * tq + i][tc] = (float)mm;
        }
        __syncthreads();
        if (t < 64) {
            float tmv = redm[t][0];
#pragma unroll
            for (int x = 1; x < 16; x++) tmv = fmaxf(tmv, redm[t][x]);
            float mo = mrow[t];
            float mn = fmaxf(mo, tmv);
            arow[t] = (mo < -1.0e37f) ? 0.0f
                       : (float)exp(0.125 * ((double)mo - (double)mn));
            mrow[t] = mn;
        }
        __syncthreads();
#pragma unroll
        for (int i = 0; i < 4; i++) {
            double mn = (double)mrow[4 * tq + i];
            float ls = 0.0f;
#pragma unroll
            for (int jj = 0; jj < 4; jj++) {
                float p = (float)exp(0.125 * (Sd[i][jj] - mn));
                KPs[4 * tc + jj][4 * tq + i] = p;
                ls += p;
            }
            redl[4 * tq + i][tc] = ls;
        }
        __syncthreads();
        if (t < 64) {
            float s = 0.0f;
#pragma unroll
            for (int x = 0; x < 16; x++) s += redl[t][x];
            lrow[t] = lrow[t] * arow[t] + s;
        }
        float al[4];
#pragma unroll
        for (int i = 0; i < 4; i++) al[i] = arow[4 * tq + i];
#pragma unroll
        for (int i = 0; i < 4; i++)
#pragma unroll
            for (int jj = 0; jj < 4; jj++) O[i][jj] *= al[i];
#pragma unroll 4
        for (int c = 0; c < 64; c++) {
            float4 pa = *(const float4*)&KPs[c][4 * tq];
            float4 vb = *(const float4*)&Vs[c][4 * tc];
            float pd[4] = {pa.x, pa.y, pa.z, pa.w};
            float vd[4] = {vb.x, vb.y, vb.z, vb.w};
#pragma unroll
            for (int i = 0; i < 4; i++)
#pragma unroll
                for (int jj = 0; jj < 4; jj++)
                    O[i][jj] += pd[i] * vd[jj];
        }
    }
    __syncthreads();
#pragma unroll
    for (int i = 0; i < 4; i++) {
        float li = lrow[4 * tq + i];
        float4 o4;
        o4.x = O[i][0] / li; o4.y = O[i][1] / li;
        o4.z = O[i][2] / li; o4.w = O[i][3] / li;
        *(float4*)&pre[(((size_t)b * C_ + q0 + 4 * tq + i) * H_ + h) * KV_ + 4 * tc] = o4;
    }
}

// ---------------------------------------------------------------------------
// Residual + LayerNorm, fp64 stats, fp32 storage. In-place safe.
// ROUND-6 CHANGE: when in1 is fp32 (always on this harness), global I/O is
// float4-vectorized. LDS buf uses the slot permutation slot = tid + 256*j
// <-> element 4*tid + j so all LDS accesses keep the conflict-free
// stride-256 pattern (vector-indexed f64 LDS would be 16-way). Mean/var are
// permutation-invariant; fp64 sum reorder is ~1e-13.
// ---------------------------------------------------------------------------
template<int IN1MODE, int OUTMODE>
__global__ __launch_bounds__(256) void ln_f64(
    const void* __restrict__ in1, const float* __restrict__ in2,
    const void* __restrict__ g, const void* __restrict__ b,
    void* __restrict__ out, const int* __restrict__ flags)
{
    __shared__ double buf[M_];
    __shared__ double red[4];
    const int isf = flags[0];
    const int row = blockIdx.x;
    const size_t base = (size_t)row * M_;
    const int tid = threadIdx.x;
    const bool vec = (IN1MODE == 1) || isf;
    double s = 0.0;
    if (vec) {
        const float4 a4 = *(const float4*)((const float*)in1 + base + tid * 4);
        const float4 b4 = *(const float4*)(in2 + base + tid * 4);
        double v0 = (double)a4.x + (double)b4.x;
        double v1 = (double)a4.y + (double)b4.y;
        double v2 = (double)a4.z + (double)b4.z;
        double v3 = (double)a4.w + (double)b4.w;
        buf[tid] = v0; buf[tid + 256] = v1; buf[tid + 512] = v2; buf[tid + 768] = v3;
        s = ((v0 + v1) + (v2 + v3));
    } else {
        for (int i = tid; i < M_; i += 256) {
            double v1 = (double)ldflag(in1, base + i, isf);
            double val = v1 + (double)in2[base + i];
            buf[i] = val;
            s += val;
        }
    }
    s = blockReduceSumD(s, red, tid);
    const double mu = s * (1.0 / M_);
    double vs = 0.0;
    for (int i = tid; i < M_; i += 256) { double dd = buf[i] - mu; vs += dd * dd; }
    vs = blockReduceSumD(vs, red, tid);
    const double rstd = 1.0 / sqrt(vs * (1.0 / M_) + 1e-5);
    if (vec) {
        // element 4*tid+j lives at slot tid + 256*j
        double y0 = (buf[tid      ] - mu) * rstd * (double)ldflag(g, 4*tid+0, isf) + (double)ldflag(b, 4*tid+0, isf);
        double y1 = (buf[tid + 256] - mu) * rstd * (double)ldflag(g, 4*tid+1, isf) + (double)ldflag(b, 4*tid+1, isf);
        double y2 = (buf[tid + 512] - mu) * rstd * (double)ldflag(g, 4*tid+2, isf) + (double)ldflag(b, 4*tid+2, isf);
        double y3 = (buf[tid + 768] - mu) * rstd * (double)ldflag(g, 4*tid+3, isf) + (double)ldflag(b, 4*tid+3, isf);
        if (OUTMODE == 0 || isf) {
            float4 o4;
            o4.x = (float)y0; o4.y = (float)y1; o4.z = (float)y2; o4.w = (float)y3;
            *(float4*)((float*)out + base + tid * 4) = o4;
        } else {
            u16* op = (u16*)out + base + tid * 4;
            op[0] = f2bf((float)y0); op[1] = f2bf((float)y1);
            op[2] = f2bf((float)y2); op[3] = f2bf((float)y3);
        }
    } else {
        for (int i = tid; i < M_; i += 256) {
            double y = (buf[i] - mu) * rstd * (double)ldflag(g, i, isf) + (double)ldflag(b, i, isf);
            if (OUTMODE == 0) ((float*)out)[base + i] = (float)y;
            else if (isf)     ((float*)out)[base + i] = (float)y;
            else              ((u16*)out)[base + i] = f2bf((float)y);
        }
    }
}

// ---------------------------------------------------------------------------
extern "C" void kernel_launch(void* const* d_in, const int* in_sizes, int n_in,
                              void* d_out, int out_size, void* d_ws, size_t ws_size,
                              hipStream_t stream)
{
    const void* enc = d_in[0];
    const void* x   = d_in[1];
    const void* wq1 = d_in[2];
    const void* wk1 = d_in[3];
    const void* wv1 = d_in[4];
    const void* wo1 = d_in[5];
    const void* g1  = d_in[6];
    const void* b1  = d_in[7];
    const void* wq2 = d_in[8];
    const void* wk2 = d_in[9];
    const void* wv2 = d_in[10];
    const void* wo2 = d_in[11];
    const void* g2  = d_in[12];
    const void* b2  = d_in[13];
    const void* fw1 = d_in[14];
    const void* fb1 = d_in[15];
    const void* fw2 = d_in[16];
    const void* fb2 = d_in[17];
    const void* g3  = d_in[18];
    const void* b3  = d_in[19];

    int* fl = (int*)d_ws;
    int* cal = fl + 16;                                // [0]=ok, [16..] lane table
    const size_t NQ = (size_t)B_ * C_ * M_;            // 4,194,304
    // Aliasing as the PASSING rounds:
    // S0: q1/q2 -> h1[0] | S1: k1->attout1->k2->attout2 -> h1[1]
    // S2: v1->v2 -> h1[2] | S3: pre1->pre2 -> h1[3] | S4: n1 -> n2 (in-place)
    // Vt scratch: attn1 -> S4 (dead until ln1), attn2 -> d_out (dead until FFN).
    float* S0 = (float*)((char*)d_ws + 4096);
    float* S1 = S0 + NQ;
    float* S2 = S1 + NQ;
    float* S3 = S2 + NQ;
    float* S4 = S3 + NQ;
    float* q = S0, *kk = S1, *vv = S2, *pre = S3, *attout = S1, *n1 = S4, *n2 = S4;
    float* h1 = S0;                                    // fp32 [4096,4096] = S0..S3
    float* ff = (float*)d_out;
    u16* vt1h = (u16*)S4;                              // 2*16*64*2048 u16 = 8.39MB
    u16* vt1l = vt1h + (size_t)B_ * H_ * KV_ * C_;
    u16* vt2h = (u16*)d_out;
    u16* vt2l = vt2h + (size_t)B_ * H_ * KV_ * C_;

    dim3 blk(256);
    dim3 gproj(C_ / 64, KV_ / 64, B_ * H_);            // (32,1,32)
    dim3 gout(B_ * C_ / 64, M_ / 64, 1);               // (64,16,1)
    dim3 gffn1(B_ * C_ / 64, F_ / 64, 1);              // (64,64,1)
    dim3 gffn2(B_ * C_ / 64, M_ / 64, 1);              // (64,16,1)
    dim3 gattn(B_ * H_ * (C_ / 64));                   // 1024
    dim3 gvt(C_ / 64, B_ * H_);                        // (32,32)
    dim3 gln(B_ * C_);                                 // 4096
    const long long AB = (long long)C_ * M_, BH = (long long)M_ * KV_, CZ = (long long)C_ * KV_;

    detect_dtype<<<1, 256, 0, stream>>>((const unsigned int*)wq1, fl);
    calibrate<<<1, 256, 0, stream>>>(cal);

    // ---- self-attention (masked) ----
    proj_qk64<0><<<gproj, blk, 0, stream>>>(x, wq1, q,  fl, cal, KV_, M_, AB, BH, CZ, H_);
    proj_qk64<0><<<gproj, blk, 0, stream>>>(x, wk1, kk, fl, cal, KV_, M_, AB, BH, CZ, H_);
    gemm_hilo<0,false,false><<<gproj, blk, 0, stream>>>(x, wv1, vv, nullptr, fl, KV_, M_, AB, BH, CZ, H_);
    v_to_bf16t<<<gvt, blk, 0, stream>>>(vv, vt1h, vt1l);
    attn_fast<<<gattn, blk, 0, stream>>>(q, kk, vt1h, vt1l, pre, cal, 1);
    attn_legacy<<<gattn, blk, 0, stream>>>(q, kk, vv, pre, cal, 1);
    gemm_hilo<1,false,false><<<gout, blk, 0, stream>>>(pre, wo1, attout, nullptr, fl, M_, M_, 0, 0, 0, 1);
    ln_f64<0, 0><<<gln, blk, 0, stream>>>(x, attout, g1, b1, n1, fl);

    // ---- cross-attention ----
    proj_qk64<1><<<gproj, blk, 0, stream>>>(n1, wq2, q,  fl, cal, KV_, M_, AB, BH, CZ, H_);
    proj_qk64<0><<<gproj, blk, 0, stream>>>(enc, wk2, kk, fl, cal, KV_, M_, AB, BH, CZ, H_);
    gemm_hilo<0,false,false><<<gproj, blk, 0, stream>>>(enc, wv2, vv, nullptr, fl, KV_, M_, AB, BH, CZ, H_);
    v_to_bf16t<<<gvt, blk, 0, stream>>>(vv, vt2h, vt2l);
    attn_fast<<<gattn, blk, 0, stream>>>(q, kk, vt2h, vt2l, pre, cal, 0);
    attn_legacy<<<gattn, blk, 0, stream>>>(q, kk, vv, pre, cal, 0);
    gemm_hilo<1,false,false><<<gout, blk, 0, stream>>>(pre, wo2, attout, nullptr, fl, M_, M_, 0, 0, 0, 1);
    ln_f64<1, 0><<<gln, blk, 0, stream>>>(n1, attout, g2, b2, n2, fl);   // in-place S4

    // ---- FFN (h1 fp32 spans S0..S3; ff in d_out; LN3 in-place) ----
    gemm_hilo<1,true,true><<<gffn1, blk, 0, stream>>>(n2, fw1, h1, fb1, fl, F_, M_, 0, 0, 0, 1);
    gemm_hilo<1,false,true><<<gffn2, blk, 0, stream>>>(h1, fw2, ff, fb2, fl, M_, F_, 0, 0, 0, 1);
    ln_f64<1, 1><<<gln, blk, 0, stream>>>(n2, ff, g3, b3, d_out, fl);
}